// Round 12
// baseline (548.765 us; speedup 1.0000x reference)
//
#include <hip/hip_runtime.h>
#include <hip/hip_cooperative_groups.h>
#include <math.h>

namespace cg = cooperative_groups;

#define BB 16
#define NN 512
#define KNN 8
#define SEQ 12
#define TQK 16          // knn: threads per query (512-thread blocks)
#define QB 32           // knn: queries per block
#define PB 16           // cells: points per block

typedef __attribute__((ext_vector_type(8))) short bf8_t;   // 8 bf16 (4 VGPRs)
typedef __attribute__((ext_vector_type(4))) float f4_t;    // MFMA acc
typedef unsigned long long ull;

__device__ __forceinline__ ushort f2b(float x) {           // fp32 -> bf16 RNE
    uint u = __float_as_uint(x);
    return (ushort)((u + 0x7fffu + ((u >> 16) & 1u)) >> 16);
}
__device__ __forceinline__ float b2f(ushort h) {
    return __uint_as_float((uint)h << 16);
}

// ---------------------------------------------------------------------------
// System-scope (coherence-point) access helpers: cross-phase mutable data
// bypasses the non-coherent per-XCD L1/L2, so barriers need no cache flush.
// ---------------------------------------------------------------------------
__device__ __forceinline__ uint ld_sys32(const ushort* p) {
    return __hip_atomic_load((const uint*)p, __ATOMIC_RELAXED,
                             __HIP_MEMORY_SCOPE_SYSTEM);
}
__device__ __forceinline__ ull ld_sys64(const void* p) {
    return __hip_atomic_load((const ull*)p, __ATOMIC_RELAXED,
                             __HIP_MEMORY_SCOPE_SYSTEM);
}
__device__ __forceinline__ int ld_sysi(const int* p) {
    return __hip_atomic_load(p, __ATOMIC_RELAXED, __HIP_MEMORY_SCOPE_SYSTEM);
}
__device__ __forceinline__ void st_sys32(ushort* p, uint v) {
    __hip_atomic_store((uint*)p, v, __ATOMIC_RELAXED,
                       __HIP_MEMORY_SCOPE_SYSTEM);
}
__device__ __forceinline__ void st_sys64(void* p, ull v) {
    __hip_atomic_store((ull*)p, v, __ATOMIC_RELAXED,
                       __HIP_MEMORY_SCOPE_SYSTEM);
}
__device__ __forceinline__ void st_sysi(int* p, int v) {
    __hip_atomic_store(p, v, __ATOMIC_RELAXED, __HIP_MEMORY_SCOPE_SYSTEM);
}
__device__ __forceinline__ void st_sysf(float* p, float v) {
    __hip_atomic_store(p, v, __ATOMIC_RELAXED, __HIP_MEMORY_SCOPE_SYSTEM);
}
__device__ __forceinline__ void st_sys_u4(ushort* p, ushort4 v) {
    union { ushort4 s; ull u; } c; c.s = v;
    st_sys64(p, c.u);
}
__device__ __forceinline__ bf8_t ld_sys_b128(const ushort* p) {
    union { ull u[2]; bf8_t v; } c;
    c.u[0] = ld_sys64(p);
    c.u[1] = ld_sys64(p + 4);
    return c.v;
}

// ---------------------------------------------------------------------------
// Shared-memory layouts. dsp/jss are PERSISTENT (outside the overlay) so P0
// can be prefetched during the previous gemm/knn phase.
// ---------------------------------------------------------------------------
struct PersistSM {                              // 6144 B, survives barriers
    float dsp[3][PB][KNN][3];
    int   jss[3][PB][KNN];
};
struct CellsRest {                              // 55296 B
    float s2s[PB][132];                         // base2 fp32 (P2 -> P3)
    float s3f[PB][260];                         // base3 fp32 (P4 -> P5)
    union { ushort s1b[2][PB][72]; float hs[PB][64]; } u1;
    ushort s2b[2][PB][136];                     // s2 bf16 (P3 -> P4)
    ushort s3c[2][PB][264];                     // s3 bf16 (P5 -> P6)
};
union __align__(16) SMU {                       // 55296 B overlay
    CellsRest c;
    ushort  g[256 * 40 + 2 * 128 * 40];         // gemm staging, 40960 B
    float   kf[1544 + 4608 + 4608];             // knn, 43040 B
};

// ---------------------------------------------------------------------------
// Group barrier: 64 blocks (bx%8 == g), fence-free (data is system-scoped).
// ---------------------------------------------------------------------------
#define GRPN 64
__device__ __forceinline__ void group_barrier(int* __restrict__ bar, int g,
                                              int target, int tid) {
    __syncthreads();
    if (tid == 0) {
        __hip_atomic_fetch_add(&bar[g * 32], 1, __ATOMIC_RELAXED,
                               __HIP_MEMORY_SCOPE_SYSTEM);
        while (__hip_atomic_load(&bar[g * 32], __ATOMIC_RELAXED,
                                 __HIP_MEMORY_SCOPE_SYSTEM) < target)
            __builtin_amdgcn_s_sleep(4);
    }
    __syncthreads();
}

// ---------------------------------------------------------------------------
// KNN for 512 threads (exact top-8). idx outputs are system stores.
// ---------------------------------------------------------------------------
__device__ __forceinline__ void knn512(
        const float* __restrict__ xqp, int xq_bs,
        const float* __restrict__ xsp, int xs_bs,
        int* __restrict__ idx1, int* __restrict__ idx2, int* __restrict__ idx3,
        float r2a, float r2b, float r2c,
        int ntile, int b, float* __restrict__ smf) {
    float* s   = smf;                           // NN*3 + NN/64 = 1544 floats
    float* cdp = smf + 1544;                    // [QB][TQK][KNN+1] = 4608
    int*   cip = (int*)(smf + 1544 + 4608);     // [QB][TQK][KNN+1] = 4608
    const int tid = threadIdx.x;

    {   // stage support points (512 threads, one each)
        int j = tid;
        const float* p = xsp + (long)b * xs_bs + j * 3;
        int o = 3 * j + (j >> 6);
        s[o + 0] = p[0]; s[o + 1] = p[1]; s[o + 2] = p[2];
    }
    __syncthreads();

    int qi  = tid >> 4;            // 0..31
    int sub = tid & 15;            // 0..15
    int n = ntile * QB + qi;
    const float* q = xqp + (long)b * xq_bs + n * 3;
    float qx = q[0], qy = q[1], qz2 = q[2];

    float bd[KNN];
    int   bi[KNN];
#pragma unroll
    for (int k = 0; k < KNN; ++k) { bd[k] = 1e30f; bi[k] = 0; }

    int j0 = sub * (NN / TQK);     // 32-point chunk (no 64-pad crossing)
    int sbase = 3 * j0 + (j0 >> 6);
#pragma unroll 4
    for (int jj = 0; jj < NN / TQK; ++jj) {
        float dx = s[sbase + 3 * jj + 0] - qx;
        float dy = s[sbase + 3 * jj + 1] - qy;
        float dz = s[sbase + 3 * jj + 2] - qz2;
        float d2 = fmaf(dx, dx, fmaf(dy, dy, dz * dz));
        if (d2 < bd[KNN - 1]) {
            bd[KNN - 1] = d2; bi[KNN - 1] = j0 + jj;
#pragma unroll
            for (int k = KNN - 1; k >= 1; --k) {
                if (bd[k] < bd[k - 1]) {
                    float td = bd[k]; bd[k] = bd[k - 1]; bd[k - 1] = td;
                    int   ti = bi[k]; bi[k] = bi[k - 1]; bi[k - 1] = ti;
                }
            }
        }
    }

    float* cdq = cdp + (qi * TQK + sub) * (KNN + 1);
    int*   ciq = cip + (qi * TQK + sub) * (KNN + 1);
#pragma unroll
    for (int k = 0; k < KNN; ++k) { cdq[k] = bd[k]; ciq[k] = bi[k]; }
    cdq[KNN] = 1e30f; ciq[KNN] = 0x7fffffff;
    __syncthreads();

    for (int stride = TQK / 2; stride >= 1; stride >>= 1) {
        if (sub < stride) {
            float* ca = cdp + (qi * TQK + sub) * (KNN + 1);
            float* cb = cdp + (qi * TQK + sub + stride) * (KNN + 1);
            int*   ja_p = cip + (qi * TQK + sub) * (KNN + 1);
            int*   jb_p = cip + (qi * TQK + sub + stride) * (KNN + 1);
            float rd[KNN]; int ri[KNN];
            int ia = 0, ib = 0;
#pragma unroll
            for (int k = 0; k < KNN; ++k) {
                float da = ca[ia], db = cb[ib];
                int   ja = ja_p[ia], jb = jb_p[ib];
                bool ta = (da < db) || (da == db && ja < jb);
                rd[k] = ta ? da : db; ri[k] = ta ? ja : jb;
                ia += ta ? 1 : 0; ib += ta ? 0 : 1;
            }
#pragma unroll
            for (int k = 0; k < KNN; ++k) { ca[k] = rd[k]; ja_p[k] = ri[k]; }
        }
        __syncthreads();
    }

    if (sub == 0) {
        long base = ((long)(b * NN + n)) * KNN;
        float* c0  = cdp + qi * TQK * (KNN + 1);
        int*   j0p = cip + qi * TQK * (KNN + 1);
        int i0 = j0p[0];
#pragma unroll
        for (int k = 0; k < KNN; ++k) {
            float d = c0[k]; int j = j0p[k];
            st_sysi(&idx1[base + k], (d <= r2a) ? j : i0);
            st_sysi(&idx2[base + k], (d <= r2b) ? j : i0);
            st_sysi(&idx3[base + k], (d <= r2c) ? j : i0);
        }
    }
}

// ---------------------------------------------------------------------------
// P0: neighbor indices + displacements. Writes the persistent region, so it
// can run during the previous phase (prefetch) when its inputs are ready.
// ---------------------------------------------------------------------------
__device__ __forceinline__ void p0_fill(
        const float* __restrict__ xq, int xq_bs,
        const float* __restrict__ xs, int xs_bs,
        const int* __restrict__ i1, const int* __restrict__ i2,
        const int* __restrict__ i3,
        int b, int n0, long row0, int tid, PersistSM& ps) {
    for (int t = tid; t < 3 * PB * KNN; t += 512) {
        int r = t >> 7, rem = t & 127, p = rem >> 3, k = rem & 7;
        const int* ix = (r == 0) ? i1 : ((r == 1) ? i2 : i3);
        int j = ld_sysi(&ix[(row0 + p) * KNN + k]);
        ps.jss[r][p][k] = j;
        const float* sp = xs + (long)b * xs_bs + j * 3;
        const float* qp = xq + (long)b * xq_bs + (n0 + p) * 3;
        ps.dsp[r][p][k][0] = sp[0] - qp[0];
        ps.dsp[r][p][k][1] = sp[1] - qp[1];
        ps.dsp[r][p][k][2] = sp[2] - qp[2];
    }
}

// ---------------------------------------------------------------------------
// 512-thread GEMM tile, 128 rows x NC cols, K=N. One tile per block.
// ---------------------------------------------------------------------------
template<int N, int NC>
__device__ __forceinline__ void gemmTileW(
        const ushort* __restrict__ Ah, const ushort* __restrict__ Al,
        const ushort* __restrict__ Bh, const ushort* __restrict__ Bl,
        ushort* __restrict__ G, int rb, int cb, int tid, ushort* lds) {
    const int row0 = rb * 128, c0 = cb * NC;
    ushort* ah = lds;                           // 128 x 40
    ushort* al = lds + 128 * 40;
    ushort* bh = lds + 256 * 40;                // NC x 40
    ushort* bl = lds + 256 * 40 + NC * 40;
    const int wv = tid >> 6, lane = tid & 63;
    const int m = lane & 15, quad = lane >> 4;
    const int lr = tid >> 2, ls = (tid & 3) * 8;    // 128 rows x 4 chunks

    f4_t acc[NC / 16];
#pragma unroll
    for (int ct = 0; ct < NC / 16; ++ct) acc[ct] = (f4_t){0.f, 0.f, 0.f, 0.f};

    bf8_t pa_h = ld_sys_b128(Ah + (long)(row0 + lr) * N + ls);
    bf8_t pa_l = ld_sys_b128(Al + (long)(row0 + lr) * N + ls);
    bf8_t pb_h, pb_l;
    const int lrB = (NC == 128) ? lr : (lr & 63);
    if (NC == 128) {
        pb_h = *(const bf8_t*)(Bh + (long)(c0 + lrB) * N + ls);
        pb_l = *(const bf8_t*)(Bl + (long)(c0 + lrB) * N + ls);
    } else {                       // NC==64: half threads h, half l
        const ushort* Bs = (tid < 256) ? Bh : Bl;
        pb_h = *(const bf8_t*)(Bs + (long)(c0 + lrB) * N + ls);
    }

    for (int k0 = 0; k0 < N; k0 += 32) {
        __syncthreads();
        *(bf8_t*)(ah + lr * 40 + ls) = pa_h;
        *(bf8_t*)(al + lr * 40 + ls) = pa_l;
        if (NC == 128) {
            *(bf8_t*)(bh + lrB * 40 + ls) = pb_h;
            *(bf8_t*)(bl + lrB * 40 + ls) = pb_l;
        } else {
            ushort* bs = (tid < 256) ? bh : bl;
            *(bf8_t*)(bs + lrB * 40 + ls) = pb_h;
        }
        __syncthreads();
        if (k0 + 32 < N) {
            int kn = k0 + 32;
            pa_h = ld_sys_b128(Ah + (long)(row0 + lr) * N + kn + ls);
            pa_l = ld_sys_b128(Al + (long)(row0 + lr) * N + kn + ls);
            if (NC == 128) {
                pb_h = *(const bf8_t*)(Bh + (long)(c0 + lrB) * N + kn + ls);
                pb_l = *(const bf8_t*)(Bl + (long)(c0 + lrB) * N + kn + ls);
            } else {
                const ushort* Bs = (tid < 256) ? Bh : Bl;
                pb_h = *(const bf8_t*)(Bs + (long)(c0 + lrB) * N + kn + ls);
            }
        }
        bf8_t a_h = *(const bf8_t*)(ah + (wv * 16 + m) * 40 + quad * 8);
        bf8_t a_l = *(const bf8_t*)(al + (wv * 16 + m) * 40 + quad * 8);
#pragma unroll
        for (int ct = 0; ct < NC / 16; ++ct) {
            bf8_t bth = *(const bf8_t*)(bh + (ct * 16 + m) * 40 + quad * 8);
            bf8_t btl = *(const bf8_t*)(bl + (ct * 16 + m) * 40 + quad * 8);
            acc[ct] = __builtin_amdgcn_mfma_f32_16x16x32_bf16(a_h, bth, acc[ct], 0, 0, 0);
            acc[ct] = __builtin_amdgcn_mfma_f32_16x16x32_bf16(a_h, btl, acc[ct], 0, 0, 0);
            acc[ct] = __builtin_amdgcn_mfma_f32_16x16x32_bf16(a_l, bth, acc[ct], 0, 0, 0);
        }
    }
#pragma unroll
    for (int ct = 0; ct < NC / 16; ++ct) {
        int col = c0 + ct * 16 + m;          // m even/odd lane pairs
#pragma unroll
        for (int r = 0; r < 4; ++r) {
            ushort v = f2b(acc[ct][r]);
            ushort vn = (ushort)__shfl_down((int)v, 1);
            if (!(m & 1))
                st_sys32(G + (long)(row0 + wv * 16 + quad * 4 + r) * N + col,
                         (uint)v | ((uint)vn << 16));
        }
    }
}

// One gemm work item per block: group-affine.
__device__ __forceinline__ void gemm_dispatch(
        int it, int tid, ushort* lds,
        const ushort* s1h, const ushort* s1l,
        const ushort* s2h, const ushort* s2l,
        const ushort* s3h, const ushort* s3l,
        const ushort* w1h, const ushort* w1l,
        const ushort* w2h, const ushort* w2l,
        const ushort* w3h, const ushort* w3l,
        ushort* G1, ushort* G2, ushort* G3) {
    int g = it & 7, j = it >> 3;               // j in [0,32)
    if (j < 16)
        gemmTileW<256, 128>(s3h, s3l, w3h, w3l, G3, g * 8 + (j & 7), j >> 3,
                            tid, lds);
    else if (j < 24)
        gemmTileW<128, 128>(s2h, s2l, w2h, w2l, G2, g * 8 + (j - 16), 0,
                            tid, lds);
    else
        gemmTileW<64, 64>(s1h, s1l, w1h, w1l, G1, g * 8 + (j - 24), 0,
                          tid, lds);
}

// ---------------------------------------------------------------------------
// Cells phase. When skip_p0, the P0 data is already in the persistent LDS
// region (prefetched during the previous phase).
// ---------------------------------------------------------------------------
__device__ __forceinline__ void cells_phase(
        bool first, int skip_p0,
        const float* __restrict__ xq, int xq_bs,
        const float* __restrict__ xs, int xs_bs,
        const int* __restrict__ i1, const int* __restrict__ i2,
        const int* __restrict__ i3,
        const ushort* __restrict__ G1p, const ushort* __restrict__ G2p,
        const ushort* __restrict__ G3p,
        ushort* __restrict__ s1h, ushort* __restrict__ s1l,
        ushort* __restrict__ s2h, ushort* __restrict__ s2l,
        ushort* __restrict__ s3h, ushort* __restrict__ s3l,
        const float* __restrict__ W1, const float* __restrict__ b1,
        const float* __restrict__ W2, const float* __restrict__ b2,
        const float* __restrict__ W3, const float* __restrict__ b3,
        const ushort* __restrict__ w2fh, const ushort* __restrict__ w2fl,
        const ushort* __restrict__ w3fh, const ushort* __restrict__ w3fl,
        const ushort* __restrict__ wmh, const ushort* __restrict__ wml,
        const float* __restrict__ bm,
        const float* __restrict__ Wl, const float* __restrict__ bl,
        float* __restrict__ xnext, int xn_bs, int do_head,
        int blk, int tid, PersistSM& ps, CellsRest& sm) {
    const int xcd = blk & 7, slot = blk >> 3;
    const int b   = xcd * 2 + (slot >> 5);     // batch <-> group affinity
    const int n0  = (slot & 31) << 4;
    const long row0 = (long)b * NN + n0;
    const long bN = (long)b * NN;
    const int wv = tid >> 6, lane = tid & 63;
    const int fm = lane & 15, quad = lane >> 4;

    if (!skip_p0) {
        p0_fill(xq, xq_bs, xs, xs_bs, i1, i2, i3, b, n0, row0, tid, ps);
        __syncthreads();
    }

    // P1: cell1 combine -> s1 bf16 (LDS) + lane-paired system global store
    {
        int co = tid & 63, q = tid >> 6;
        float g1r[2][KNN];
        if (!first) {
#pragma unroll
            for (int r = 0; r < 2; ++r)
#pragma unroll
                for (int k = 0; k < KNN; ++k) {
                    uint vv = ld_sys32(G1p + (bN + ps.jss[0][2 * q + r][k]) * 64
                                       + (co & ~1));
                    ushort hv = (co & 1) ? (ushort)(vv >> 16) : (ushort)vv;
                    g1r[r][k] = b2f(hv);
                }
        }
        float wx = W1[co], wy = W1[64 + co], wz = W1[128 + co];
        float bz = b1[co];
#pragma unroll
        for (int r = 0; r < 2; ++r) {
            int p = 2 * q + r;
            float acc = -1e30f;
#pragma unroll
            for (int k = 0; k < KNN; ++k) {
                float v = fmaf(ps.dsp[0][p][k][0], wx, bz);
                v = fmaf(ps.dsp[0][p][k][1], wy, v);
                v = fmaf(ps.dsp[0][p][k][2], wz, v);
                if (!first) v += g1r[r][k];
                acc = fmaxf(acc, v);
            }
            ushort h = f2b(acc);
            ushort l = f2b(acc - b2f(h));
            sm.u1.s1b[0][p][co] = h;
            sm.u1.s1b[1][p][co] = l;
            ushort hn = (ushort)__shfl_down((int)h, 1);
            ushort ln = (ushort)__shfl_down((int)l, 1);
            if (!(co & 1)) {
                st_sys32(s1h + (row0 + p) * 64 + co, (uint)h | ((uint)hn << 16));
                st_sys32(s1l + (row0 + p) * 64 + co, (uint)l | ((uint)ln << 16));
            }
        }
    }
    __syncthreads();

    // G2 gathers prefetched (system 8B -> fp32), hidden behind base2 MFMA
    float4 g2r[KNN];
    {
        int c4 = tid & 31, g = tid >> 5;
        if (!first) {
#pragma unroll
            for (int k = 0; k < KNN; ++k) {
                ull v = ld_sys64(&G2p[(bN + ps.jss[1][g][k]) * 128 + c4 * 4]);
                g2r[k] = make_float4(b2f((ushort)v), b2f((ushort)(v >> 16)),
                                     b2f((ushort)(v >> 32)), b2f((ushort)(v >> 48)));
            }
        }
    }

    // P2: base2 = s1 @ W2f + b2 on MFMA -> s2s
    {
        int col = wv * 16 + fm;
        float bz = b2[col];
        f4_t acc = {bz, bz, bz, bz};
#pragma unroll
        for (int k0 = 0; k0 < 64; k0 += 32) {
            bf8_t ah = *(const bf8_t*)&sm.u1.s1b[0][fm][k0 + quad * 8];
            bf8_t al = *(const bf8_t*)&sm.u1.s1b[1][fm][k0 + quad * 8];
            bf8_t bh = *(const bf8_t*)(w2fh + col * 64 + k0 + quad * 8);
            bf8_t bl = *(const bf8_t*)(w2fl + col * 64 + k0 + quad * 8);
            acc = __builtin_amdgcn_mfma_f32_16x16x32_bf16(ah, bh, acc, 0, 0, 0);
            acc = __builtin_amdgcn_mfma_f32_16x16x32_bf16(ah, bl, acc, 0, 0, 0);
            acc = __builtin_amdgcn_mfma_f32_16x16x32_bf16(al, bh, acc, 0, 0, 0);
        }
#pragma unroll
        for (int r = 0; r < 4; ++r) sm.s2s[quad * 4 + r][col] = acc[r];
    }
    __syncthreads();

    // P3: combine2 -> s2 bf16 (LDS) + system global store (8B)
    {
        int c4 = tid & 31, g = tid >> 5;
        float4 bse = *(float4*)&sm.s2s[g][c4 * 4];
        float4 wx = ((const float4*)W2)[c4];
        float4 wy = ((const float4*)(W2 + 128))[c4];
        float4 wz = ((const float4*)(W2 + 256))[c4];
        float4 m = make_float4(-1e30f, -1e30f, -1e30f, -1e30f);
#pragma unroll
        for (int k = 0; k < KNN; ++k) {
            float dx = ps.dsp[1][g][k][0], dy = ps.dsp[1][g][k][1],
                  dz = ps.dsp[1][g][k][2];
            float4 v;
            v.x = fmaf(dz, wz.x, fmaf(dy, wy.x, fmaf(dx, wx.x, bse.x)));
            v.y = fmaf(dz, wz.y, fmaf(dy, wy.y, fmaf(dx, wx.y, bse.y)));
            v.z = fmaf(dz, wz.z, fmaf(dy, wy.z, fmaf(dx, wx.z, bse.z)));
            v.w = fmaf(dz, wz.w, fmaf(dy, wy.w, fmaf(dx, wx.w, bse.w)));
            if (!first) {
                v.x += g2r[k].x; v.y += g2r[k].y;
                v.z += g2r[k].z; v.w += g2r[k].w;
            }
            m.x = fmaxf(m.x, v.x); m.y = fmaxf(m.y, v.y);
            m.z = fmaxf(m.z, v.z); m.w = fmaxf(m.w, v.w);
        }
        ushort4 mh, ml;
        mh.x = f2b(m.x); ml.x = f2b(m.x - b2f(mh.x));
        mh.y = f2b(m.y); ml.y = f2b(m.y - b2f(mh.y));
        mh.z = f2b(m.z); ml.z = f2b(m.z - b2f(mh.z));
        mh.w = f2b(m.w); ml.w = f2b(m.w - b2f(mh.w));
        *(ushort4*)&sm.s2b[0][g][c4 * 4] = mh;
        *(ushort4*)&sm.s2b[1][g][c4 * 4] = ml;
        st_sys_u4(&s2h[(row0 + g) * 128 + c4 * 4], mh);
        st_sys_u4(&s2l[(row0 + g) * 128 + c4 * 4], ml);
    }
    __syncthreads();

    // G3 gathers prefetched (system 8B -> fp32), hidden behind base3 MFMA
    float4 g3r[2][KNN];
    {
        int c4 = tid & 63, g = tid >> 6;
        if (!first) {
#pragma unroll
            for (int r = 0; r < 2; ++r)
#pragma unroll
                for (int k = 0; k < KNN; ++k) {
                    ull v = ld_sys64(&G3p[(bN + ps.jss[2][2 * g + r][k]) * 256 + c4 * 4]);
                    g3r[r][k] = make_float4(b2f((ushort)v), b2f((ushort)(v >> 16)),
                                            b2f((ushort)(v >> 32)), b2f((ushort)(v >> 48)));
                }
        }
    }

    // P4: base3 = s2 @ W3f + b3 on MFMA -> s3f (2 column tiles per wave)
    {
        int col0 = wv * 16 + fm, col1 = (wv + 8) * 16 + fm;
        float bz0 = b3[col0], bz1 = b3[col1];
        f4_t a0 = {bz0, bz0, bz0, bz0};
        f4_t a1 = {bz1, bz1, bz1, bz1};
#pragma unroll
        for (int k0 = 0; k0 < 128; k0 += 32) {
            bf8_t ah = *(const bf8_t*)&sm.s2b[0][fm][k0 + quad * 8];
            bf8_t al = *(const bf8_t*)&sm.s2b[1][fm][k0 + quad * 8];
            bf8_t b0h = *(const bf8_t*)(w3fh + col0 * 128 + k0 + quad * 8);
            bf8_t b0l = *(const bf8_t*)(w3fl + col0 * 128 + k0 + quad * 8);
            bf8_t b1h = *(const bf8_t*)(w3fh + col1 * 128 + k0 + quad * 8);
            bf8_t b1l = *(const bf8_t*)(w3fl + col1 * 128 + k0 + quad * 8);
            a0 = __builtin_amdgcn_mfma_f32_16x16x32_bf16(ah, b0h, a0, 0, 0, 0);
            a0 = __builtin_amdgcn_mfma_f32_16x16x32_bf16(ah, b0l, a0, 0, 0, 0);
            a0 = __builtin_amdgcn_mfma_f32_16x16x32_bf16(al, b0h, a0, 0, 0, 0);
            a1 = __builtin_amdgcn_mfma_f32_16x16x32_bf16(ah, b1h, a1, 0, 0, 0);
            a1 = __builtin_amdgcn_mfma_f32_16x16x32_bf16(ah, b1l, a1, 0, 0, 0);
            a1 = __builtin_amdgcn_mfma_f32_16x16x32_bf16(al, b1h, a1, 0, 0, 0);
        }
#pragma unroll
        for (int r = 0; r < 4; ++r) {
            sm.s3f[quad * 4 + r][col0] = a0[r];
            sm.s3f[quad * 4 + r][col1] = a1[r];
        }
    }
    __syncthreads();

    // P5: combine3 -> s3 bf16 (LDS) + system global store (8B)
    {
        int c4 = tid & 63, g = tid >> 6;
        float4 wx = ((const float4*)W3)[c4];
        float4 wy = ((const float4*)(W3 + 256))[c4];
        float4 wz = ((const float4*)(W3 + 512))[c4];
#pragma unroll
        for (int r = 0; r < 2; ++r) {
            int p = 2 * g + r;
            float4 bse = *(float4*)&sm.s3f[p][c4 * 4];
            float4 m = make_float4(-1e30f, -1e30f, -1e30f, -1e30f);
#pragma unroll
            for (int k = 0; k < KNN; ++k) {
                float dx = ps.dsp[2][p][k][0], dy = ps.dsp[2][p][k][1],
                      dz = ps.dsp[2][p][k][2];
                float4 v;
                v.x = fmaf(dz, wz.x, fmaf(dy, wy.x, fmaf(dx, wx.x, bse.x)));
                v.y = fmaf(dz, wz.y, fmaf(dy, wy.y, fmaf(dx, wx.y, bse.y)));
                v.z = fmaf(dz, wz.z, fmaf(dy, wy.z, fmaf(dx, wx.z, bse.z)));
                v.w = fmaf(dz, wz.w, fmaf(dy, wy.w, fmaf(dx, wx.w, bse.w)));
                if (!first) {
                    v.x += g3r[r][k].x; v.y += g3r[r][k].y;
                    v.z += g3r[r][k].z; v.w += g3r[r][k].w;
                }
                m.x = fmaxf(m.x, v.x); m.y = fmaxf(m.y, v.y);
                m.z = fmaxf(m.z, v.z); m.w = fmaxf(m.w, v.w);
            }
            ushort4 mh, ml;
            mh.x = f2b(m.x); ml.x = f2b(m.x - b2f(mh.x));
            mh.y = f2b(m.y); ml.y = f2b(m.y - b2f(mh.y));
            mh.z = f2b(m.z); ml.z = f2b(m.z - b2f(mh.z));
            mh.w = f2b(m.w); ml.w = f2b(m.w - b2f(mh.w));
            *(ushort4*)&sm.s3c[0][p][c4 * 4] = mh;
            *(ushort4*)&sm.s3c[1][p][c4 * 4] = ml;
            st_sys_u4(&s3h[(row0 + p) * 256 + c4 * 4], mh);
            st_sys_u4(&s3l[(row0 + p) * 256 + c4 * 4], ml);
        }
    }

    // P6: prediction head — h = relu(s3 @ Wm + bm) on MFMA, then motion
    if (do_head) {
        __syncthreads();
        if (wv < 4) {
            int col = wv * 16 + fm;
            float bz = bm[col];
            f4_t acc = {bz, bz, bz, bz};
#pragma unroll
            for (int k0 = 0; k0 < 256; k0 += 32) {
                bf8_t ah = *(const bf8_t*)&sm.s3c[0][fm][k0 + quad * 8];
                bf8_t al = *(const bf8_t*)&sm.s3c[1][fm][k0 + quad * 8];
                bf8_t bh = *(const bf8_t*)(wmh + col * 256 + k0 + quad * 8);
                bf8_t bl = *(const bf8_t*)(wml + col * 256 + k0 + quad * 8);
                acc = __builtin_amdgcn_mfma_f32_16x16x32_bf16(ah, bh, acc, 0, 0, 0);
                acc = __builtin_amdgcn_mfma_f32_16x16x32_bf16(ah, bl, acc, 0, 0, 0);
                acc = __builtin_amdgcn_mfma_f32_16x16x32_bf16(al, bh, acc, 0, 0, 0);
            }
            __syncthreads();   // u1.s1b dead since P2; reuse as hs
#pragma unroll
            for (int r = 0; r < 4; ++r)
                sm.u1.hs[quad * 4 + r][col] = fmaxf(acc[r], 0.f);
        } else {
            __syncthreads();
        }
        __syncthreads();
        if (tid < PB * 3) {
            int p = tid / 3, d = tid % 3;
            float m = bl[d];
#pragma unroll 4
            for (int c = 0; c < 64; ++c)
                m = fmaf(sm.u1.hs[p][c], Wl[c * 3 + d], m);
            const float* qp = xq + (long)b * xq_bs + (n0 + p) * 3;
            st_sysf(&xnext[(long)b * xn_bs + (n0 + p) * 3 + d], qp[d] + m);
        }
    }
}

// ---------------------------------------------------------------------------
// Weight conversion helper (flat id). Plain stores; ordered by grid.sync.
// ---------------------------------------------------------------------------
__device__ __forceinline__ void convW_one(int id,
        const float* __restrict__ W1, const float* __restrict__ W2,
        const float* __restrict__ W3, const float* __restrict__ Wm,
        ushort* w1h, ushort* w1l, ushort* w2h, ushort* w2l,
        ushort* w3h, ushort* w3l, ushort* w2fh, ushort* w2fl,
        ushort* w3fh, ushort* w3fl, ushort* wmh, ushort* wml) {
    float v; ushort* ph; ushort* pl; int idx;
    if (id < 4096)        { int n = id >> 6, k = id & 63;
        v = W1[(3 + k) * 64 + n];   ph = w1h;  pl = w1l;  idx = id; }
    else if (id < 20480)  { int u = id - 4096, n = u >> 7, k = u & 127;
        v = W2[(67 + k) * 128 + n]; ph = w2h;  pl = w2l;  idx = u; }
    else if (id < 86016)  { int u = id - 20480, n = u >> 8, k = u & 255;
        v = W3[(131 + k) * 256 + n]; ph = w3h; pl = w3l;  idx = u; }
    else if (id < 94208)  { int u = id - 86016, n = u >> 6, k = u & 63;
        v = W2[(3 + k) * 128 + n];  ph = w2fh; pl = w2fl; idx = u; }
    else if (id < 126976) { int u = id - 94208, n = u >> 7, k = u & 127;
        v = W3[(3 + k) * 256 + n];  ph = w3fh; pl = w3fl; idx = u; }
    else if (id < 143360) { int u = id - 126976, n = u >> 8, k = u & 255;
        v = Wm[k * 64 + n];         ph = wmh;  pl = wml;  idx = u; }
    else return;
    ushort h = f2b(v);
    ph[idx] = h; pl[idx] = f2b(v - b2f(h));
}

// ---------------------------------------------------------------------------
// FUSED cooperative kernel.
// Schedule: init (convW + knn slots 0,1) -> [cells(t) | gemm(t)+knn(slot
// t+2 for t<=4, slot 0 for t>=6) + P0-prefetch(t+1<=6)] x 12.
// ---------------------------------------------------------------------------
__global__ __launch_bounds__(512, 4) void fused_kernel(
        const float* frames, float* out,
        ushort* G1, ushort* G2, ushort* G3,
        ushort* s1h, ushort* s1l, ushort* s2h, ushort* s2l,
        ushort* s3h, ushort* s3l,
        ushort* w1h, ushort* w1l, ushort* w2h, ushort* w2l,
        ushort* w3h, ushort* w3l,
        ushort* w2fh, ushort* w2fl, ushort* w3fh, ushort* w3fl,
        ushort* wmh, ushort* wml,
        int* idx1w, int* idx2w, int* idx3w, int* bar,
        const float* W1, const float* b1, const float* W2, const float* b2,
        const float* W3, const float* b3, const float* Wm, const float* bm,
        const float* Wl, const float* bl,
        float r2a, float r2b, float r2c) {
    __shared__ PersistSM ps;
    __shared__ SMU smu;
    cg::grid_group grid = cg::this_grid();
    const int bx = blockIdx.x, tid = threadIdx.x;
    const int grp = bx & 7;
    const int FB = SEQ * NN * 3, OB = 6 * NN * 3;
    const long BNK = (long)BB * NN * KNN;

    // cells identity of this block (constant across phases)
    const int c_xcd = bx & 7, c_slot = bx >> 3;
    const int c_b = c_xcd * 2 + (c_slot >> 5);
    const int c_n0 = (c_slot & 31) << 4;
    const long c_row0 = (long)c_b * NN + c_n0;

    // ---- init: barrier counters + weight conversion + knn slots 0,1 ----
    if (bx == 0 && tid < 8) st_sysi(&bar[tid * 32], 0);
    convW_one(bx * 512 + tid, W1, W2, W3, Wm,
              w1h, w1l, w2h, w2l, w3h, w3l,
              w2fh, w2fl, w3fh, w3fl, wmh, wml);
    {
        int r = bx & 255;
        int xcd = r & 7, slot = r >> 3;
        int b = xcd * 2 + (slot & 1), ntile = slot >> 1;
        if (bx < 256)        // slot 0: q = s = frames[0]
            knn512(frames, FB, frames, FB, idx1w, idx2w, idx3w,
                   r2a, r2b, r2c, ntile, b, smu.kf);
        else                 // slot 1: q = frames[1], s = frames[0]
            knn512(frames + (long)NN * 3, FB, frames, FB,
                   idx1w + BNK, idx2w + BNK, idx3w + BNK,
                   r2a, r2b, r2c, ntile, b, smu.kf);
    }
    grid.sync();

    int ph = 1;       // monotonic group-barrier phase

    for (int t = 0; t < SEQ; ++t) {
        const float* xq; int xq_bs; const float* xs; int xs_bs;
        if (t < 6)       { xq = frames + (long)t * NN * 3;        xq_bs = FB; }
        else if (t == 6) { xq = frames + 5L * NN * 3;             xq_bs = FB; }
        else             { xq = out + (long)(t - 7) * NN * 3;     xq_bs = OB; }
        if (t == 0)      { xs = xq;                               xs_bs = xq_bs; }
        else if (t <= 6) { xs = frames + (long)(t - 1) * NN * 3;  xs_bs = FB; }
        else if (t == 7) { xs = frames + 5L * NN * 3;             xs_bs = FB; }
        else             { xs = out + (long)(t - 8) * NN * 3;     xs_bs = OB; }
        int slot = (t <= 6) ? t : 0;
        const int* i1 = idx1w + slot * BNK;
        const int* i2 = idx2w + slot * BNK;
        const int* i3 = idx3w + slot * BNK;
        int do_head = (t >= 6);
        int skip_p0 = (t >= 1 && t <= 6);      // prefetched last phase
        float* xnext = do_head ? out + (long)(t - 6) * NN * 3 : nullptr;

        cells_phase(t == 0, skip_p0, xq, xq_bs, xs, xs_bs, i1, i2, i3,
                    G1, G2, G3, s1h, s1l, s2h, s2l, s3h, s3l,
                    W1, b1, W2, b2, W3, b3,
                    w2fh, w2fl, w3fh, w3fl, wmh, wml, bm,
                    Wl, bl, xnext, OB, do_head, bx, tid, ps, smu.c);

        if (t == SEQ - 1) break;
        group_barrier(bar, grp, GRPN * ph, tid); ++ph;

        // ---- gemm + knn + P0-prefetch phase ----
        if (bx < 256) {
            if (t <= 4) {
                // warm knn slot t+2 (frames only)
                int z = t + 2;
                int qz = z < 5 ? z : 5;
                int xcd = bx & 7, slot2 = bx >> 3;
                int b = xcd * 2 + (slot2 & 1), ntile = slot2 >> 1;
                knn512(frames + (long)qz * NN * 3, FB,
                       frames + (long)(z - 1) * NN * 3, FB,
                       idx1w + (long)z * BNK, idx2w + (long)z * BNK,
                       idx3w + (long)z * BNK,
                       r2a, r2b, r2c, ntile, b, smu.kf);
            } else if (t >= 6) {
                // runtime knn slot 0 for step t+1 (needs out of step t)
                int tn = t + 1;
                const float* kq = out + (long)(tn - 7) * NN * 3;
                const float* ksp; int ks_bs;
                if (tn == 7) { ksp = frames + 5L * NN * 3;          ks_bs = FB; }
                else         { ksp = out + (long)(tn - 8) * NN * 3; ks_bs = OB; }
                int xcd = bx & 7, slot2 = bx >> 3;
                int b = xcd * 2 + (slot2 & 1), ntile = slot2 >> 1;
                knn512(kq, OB, ksp, ks_bs, idx1w, idx2w, idx3w,
                       r2a, r2b, r2c, ntile, b, smu.kf);
            }
        } else {
            gemm_dispatch(bx - 256, tid, smu.g,
                          s1h, s1l, s2h, s2l, s3h, s3l,
                          w1h, w1l, w2h, w2l, w3h, w3l, G1, G2, G3);
        }

        // P0-prefetch for cells step t+1 (frames-based steps only; idx slot
        // t+1 was produced in an EARLIER phase, so it is safe to read here)
        {
            int tn = t + 1;
            if (tn <= 6) {
                const float* pq = (tn < 6) ? frames + (long)tn * NN * 3
                                           : frames + 5L * NN * 3;
                const float* psrc = frames + (long)(tn - 1) * NN * 3;
                __syncthreads();   // ensure knn/gemm LDS use is complete
                p0_fill(pq, FB, psrc, FB,
                        idx1w + (long)tn * BNK, idx2w + (long)tn * BNK,
                        idx3w + (long)tn * BNK,
                        c_b, c_n0, c_row0, tid, ps);
            }
        }
        group_barrier(bar, grp, GRPN * ph, tid); ++ph;
    }
}

// ---------------------------------------------------------------------------
// FALLBACK multi-kernel schedule (kernel boundaries provide coherence).
// Keeps the original slot schedule; cells always does its own P0.
// ---------------------------------------------------------------------------
__global__ __launch_bounds__(512) void init512_kernel(
        const float* __restrict__ frames, int FB,
        int* __restrict__ i1, int* __restrict__ i2, int* __restrict__ i3,
        float r2a, float r2b, float r2c,
        const float* __restrict__ W1, const float* __restrict__ W2,
        const float* __restrict__ W3, const float* __restrict__ Wm,
        ushort* w1h, ushort* w1l, ushort* w2h, ushort* w2l,
        ushort* w3h, ushort* w3l, ushort* w2fh, ushort* w2fl,
        ushort* w3fh, ushort* w3fl, ushort* wmh, ushort* wml) {
    __shared__ float kf[1544 + 4608 + 4608];
    int bx = blockIdx.x;
    if (bx < 256) {
        int xcd = bx & 7, slot = bx >> 3;
        int b = xcd * 2 + (slot & 1), ntile = slot >> 1;
        knn512(frames, FB, frames, FB, i1, i2, i3, r2a, r2b, r2c,
               ntile, b, kf);
        return;
    }
    convW_one((bx - 256) * 512 + threadIdx.x, W1, W2, W3, Wm,
              w1h, w1l, w2h, w2l, w3h, w3l,
              w2fh, w2fl, w3fh, w3fl, wmh, wml);
}

__global__ __launch_bounds__(512) void cells512_kernel(
        int first,
        const float* __restrict__ xq, int xq_bs,
        const float* __restrict__ xs, int xs_bs,
        const int* __restrict__ i1, const int* __restrict__ i2,
        const int* __restrict__ i3,
        const ushort* __restrict__ G1p, const ushort* __restrict__ G2p,
        const ushort* __restrict__ G3p,
        ushort* s1h, ushort* s1l, ushort* s2h, ushort* s2l,
        ushort* s3h, ushort* s3l,
        const float* __restrict__ W1, const float* __restrict__ b1,
        const float* __restrict__ W2, const float* __restrict__ b2,
        const float* __restrict__ W3, const float* __restrict__ b3,
        const ushort* __restrict__ w2fh, const ushort* __restrict__ w2fl,
        const ushort* __restrict__ w3fh, const ushort* __restrict__ w3fl,
        const ushort* __restrict__ wmh, const ushort* __restrict__ wml,
        const float* __restrict__ bm,
        const float* __restrict__ Wl, const float* __restrict__ bl,
        float* xnext, int xn_bs, int do_head) {
    __shared__ PersistSM ps;
    __shared__ CellsRest sm;
    cells_phase(first != 0, 0, xq, xq_bs, xs, xs_bs, i1, i2, i3,
                G1p, G2p, G3p, s1h, s1l, s2h, s2l, s3h, s3l,
                W1, b1, W2, b2, W3, b3, w2fh, w2fl, w3fh, w3fl,
                wmh, wml, bm, Wl, bl, xnext, xn_bs, do_head,
                blockIdx.x, threadIdx.x, ps, sm);
}

__global__ __launch_bounds__(512) void gemmknn512_kernel(
        const ushort* s1h, const ushort* s1l,
        const ushort* s2h, const ushort* s2l,
        const ushort* s3h, const ushort* s3l,
        const ushort* w1h, const ushort* w1l,
        const ushort* w2h, const ushort* w2l,
        const ushort* w3h, const ushort* w3l,
        ushort* G1, ushort* G2, ushort* G3,
        const float* __restrict__ kq, int kq_bs,
        const float* __restrict__ ks, int ks_bs,
        int* ki1, int* ki2, int* ki3,
        float r2a, float r2b, float r2c) {
    __shared__ SMU smu;
    int bx = blockIdx.x, tid = threadIdx.x;
    if (bx < 256) {
        int xcd = bx & 7, slot = bx >> 3;
        int b = xcd * 2 + (slot & 1), ntile = slot >> 1;
        knn512(kq, kq_bs, ks, ks_bs, ki1, ki2, ki3, r2a, r2b, r2c,
               ntile, b, smu.kf);
        return;
    }
    gemm_dispatch(bx - 256, tid, smu.g,
                  s1h, s1l, s2h, s2l, s3h, s3l,
                  w1h, w1l, w2h, w2l, w3h, w3l, G1, G2, G3);
}

extern "C" void kernel_launch(void* const* d_in, const int* in_sizes, int n_in,
                              void* d_out, int out_size, void* d_ws, size_t ws_size,
                              hipStream_t stream) {
    const float* frames = (const float*)d_in[0];
    const float* W1 = (const float*)d_in[1]; const float* b1 = (const float*)d_in[2];
    const float* W2 = (const float*)d_in[3]; const float* b2 = (const float*)d_in[4];
    const float* W3 = (const float*)d_in[5]; const float* b3 = (const float*)d_in[6];
    const float* Wm = (const float*)d_in[7]; const float* bm = (const float*)d_in[8];
    const float* Wl = (const float*)d_in[9]; const float* bl = (const float*)d_in[10];
    float* out = (float*)d_out;

    const long M = (long)BB * NN;    // 8192
    ushort* us = (ushort*)d_ws;
    ushort* G1b = us; us += M * 64;   // bf16 G arrays
    ushort* G2b = us; us += M * 128;
    ushort* G3b = us; us += M * 256;
    ushort* s1h = us; us += M * 64;   ushort* s1l = us; us += M * 64;
    ushort* s2h = us; us += M * 128;  ushort* s2l = us; us += M * 128;
    ushort* s3h = us; us += M * 256;  ushort* s3l = us; us += M * 256;
    ushort* w1h = us; us += 4096;     ushort* w1l = us; us += 4096;
    ushort* w2h = us; us += 16384;    ushort* w2l = us; us += 16384;
    ushort* w3h = us; us += 65536;    ushort* w3l = us; us += 65536;
    ushort* w2fh = us; us += 8192;    ushort* w2fl = us; us += 8192;
    ushort* w3fh = us; us += 32768;   ushort* w3fl = us; us += 32768;
    ushort* wmh = us; us += 16384;    ushort* wml = us; us += 16384;
    us += (size_t)us & 1;             // even-align for int
    const long BNK = M * KNN;
    int* ip = (int*)us;
    int* idx1w = ip; ip += 7 * BNK;
    int* idx2w = ip; ip += 7 * BNK;
    int* idx3w = ip; ip += 7 * BNK;
    int* bar   = ip; ip += 8 * 32;    // 8 group counters, 128B apart

    double ra = 4.0 + 1e-6, rbd = 8.0 + 1e-6, rc = 12.0 + 1e-6;
    float r2a = (float)(ra * ra), r2b = (float)(rbd * rbd), r2c = (float)(rc * rc);

    const int FB = SEQ * NN * 3;
    const int OB = 6 * NN * 3;

    // ---- capture-safe cooperative feasibility check (cached) ----
    static int g_coop = -1;
    if (g_coop < 0) {
        int attr = 0, dev = 0, nb = 0;
        hipGetDevice(&dev);
        hipDeviceGetAttribute(&attr, hipDeviceAttributeCooperativeLaunch, dev);
        hipDeviceProp_t prop{};
        hipGetDeviceProperties(&prop, dev);
        if (attr &&
            hipOccupancyMaxActiveBlocksPerMultiprocessor(
                &nb, fused_kernel, 512, 0) == hipSuccess &&
            nb * prop.multiProcessorCount >= 512)
            g_coop = 1;
        else
            g_coop = 0;
    }

    bool did_coop = false;
    if (g_coop == 1) {
        void* args[] = {
            (void*)&frames, (void*)&out,
            (void*)&G1b, (void*)&G2b, (void*)&G3b,
            (void*)&s1h, (void*)&s1l, (void*)&s2h, (void*)&s2l,
            (void*)&s3h, (void*)&s3l,
            (void*)&w1h, (void*)&w1l, (void*)&w2h, (void*)&w2l,
            (void*)&w3h, (void*)&w3l,
            (void*)&w2fh, (void*)&w2fl, (void*)&w3fh, (void*)&w3fl,
            (void*)&wmh, (void*)&wml,
            (void*)&idx1w, (void*)&idx2w, (void*)&idx3w, (void*)&bar,
            (void*)&W1, (void*)&b1, (void*)&W2, (void*)&b2,
            (void*)&W3, (void*)&b3, (void*)&Wm, (void*)&bm,
            (void*)&Wl, (void*)&bl,
            (void*)&r2a, (void*)&r2b, (void*)&r2c
        };
        hipError_t e = hipLaunchCooperativeKernel((const void*)fused_kernel,
                                                  dim3(512), dim3(512),
                                                  args, 0, stream);
        did_coop = (e == hipSuccess);
        if (!did_coop) g_coop = 0;
    }

    if (!did_coop) {
        // ---- proven multi-kernel schedule ----
        init512_kernel<<<536, 512, 0, stream>>>(
            frames, FB, idx1w, idx2w, idx3w, r2a, r2b, r2c,
            W1, W2, W3, Wm, w1h, w1l, w2h, w2l, w3h, w3l,
            w2fh, w2fl, w3fh, w3fl, wmh, wml);

        for (int t = 0; t < SEQ; ++t) {
            const float* xq; int xq_bs; const float* xs; int xs_bs;
            if (t < 6)       { xq = frames + (long)t * NN * 3;        xq_bs = FB; }
            else if (t == 6) { xq = frames + 5L * NN * 3;             xq_bs = FB; }
            else             { xq = out + (long)(t - 7) * NN * 3;     xq_bs = OB; }
            if (t == 0)      { xs = xq;                               xs_bs = xq_bs; }
            else if (t <= 6) { xs = frames + (long)(t - 1) * NN * 3;  xs_bs = FB; }
            else if (t == 7) { xs = frames + 5L * NN * 3;             xs_bs = FB; }
            else             { xs = out + (long)(t - 8) * NN * 3;     xs_bs = OB; }

            int slot = (t <= 6) ? t : 0;
            int* i1 = idx1w + (long)slot * BNK;
            int* i2 = idx2w + (long)slot * BNK;
            int* i3 = idx3w + (long)slot * BNK;

            int do_head = (t >= 6);
            float* xnext = do_head ? out + (long)(t - 6) * NN * 3 : nullptr;

            cells512_kernel<<<BB * NN / PB, 512, 0, stream>>>(
                t == 0 ? 1 : 0, xq, xq_bs, xs, xs_bs, i1, i2, i3,
                G1b, G2b, G3b, s1h, s1l, s2h, s2l, s3h, s3l,
                W1, b1, W2, b2, W3, b3,
                w2fh, w2fl, w3fh, w3fl, wmh, wml, bm,
                Wl, bl, xnext, OB, do_head);

            if (t < SEQ - 1) {
                int tn = t + 1;
                const float* kq; int kq_bs; const float* ksp; int ks_bs; int kslot;
                if (tn <= 6) {
                    int qz = tn < 5 ? tn : 5;
                    kq = frames + (long)qz * NN * 3;        kq_bs = FB;
                    ksp = frames + (long)(tn - 1) * NN * 3; ks_bs = FB;
                    kslot = tn;
                } else {
                    kq = out + (long)(tn - 7) * NN * 3;     kq_bs = OB;
                    if (tn == 7) { ksp = frames + 5L * NN * 3;          ks_bs = FB; }
                    else         { ksp = out + (long)(tn - 8) * NN * 3; ks_bs = OB; }
                    kslot = 0;
                }
                gemmknn512_kernel<<<512, 512, 0, stream>>>(
                    s1h, s1l, s2h, s2l, s3h, s3l,
                    w1h, w1l, w2h, w2l, w3h, w3l,
                    G1b, G2b, G3b,
                    kq, kq_bs, ksp, ks_bs,
                    idx1w + (long)kslot * BNK, idx2w + (long)kslot * BNK,
                    idx3w + (long)kslot * BNK,
                    r2a, r2b, r2c);
            }
        }
    }
}

// Round 13
// 508.250 us; speedup vs baseline: 1.0797x; 1.0797x over previous
//
#include <hip/hip_runtime.h>
#include <hip/hip_cooperative_groups.h>
#include <math.h>

namespace cg = cooperative_groups;

#define BB 16
#define NN 512
#define KNN 8
#define SEQ 12
#define TQK 16          // knn: threads per query (512-thread blocks)
#define QB 32           // knn: queries per block
#define PB 16           // cells: points per block

typedef __attribute__((ext_vector_type(8))) short bf8_t;   // 8 bf16 (4 VGPRs)
typedef __attribute__((ext_vector_type(4))) float f4_t;    // MFMA acc
typedef unsigned long long ull;

__device__ __forceinline__ ushort f2b(float x) {           // fp32 -> bf16 RNE
    uint u = __float_as_uint(x);
    return (ushort)((u + 0x7fffu + ((u >> 16) & 1u)) >> 16);
}
__device__ __forceinline__ float b2f(ushort h) {
    return __uint_as_float((uint)h << 16);
}

// ---------------------------------------------------------------------------
// System-scope (coherence-point) access helpers. All cross-phase mutable
// data flows through these: loads/stores bypass the (per-XCD, non-coherent)
// L1/L2, so phase barriers need NO cache-flushing fences, and read-only data
// stays hot in L1/L2 across all phases. Values are bit-identical.
// ---------------------------------------------------------------------------
__device__ __forceinline__ uint ld_sys32(const ushort* p) {
    return __hip_atomic_load((const uint*)p, __ATOMIC_RELAXED,
                             __HIP_MEMORY_SCOPE_SYSTEM);
}
__device__ __forceinline__ ull ld_sys64(const void* p) {
    return __hip_atomic_load((const ull*)p, __ATOMIC_RELAXED,
                             __HIP_MEMORY_SCOPE_SYSTEM);
}
__device__ __forceinline__ int ld_sysi(const int* p) {
    return __hip_atomic_load(p, __ATOMIC_RELAXED, __HIP_MEMORY_SCOPE_SYSTEM);
}
__device__ __forceinline__ void st_sys32(ushort* p, uint v) {
    __hip_atomic_store((uint*)p, v, __ATOMIC_RELAXED,
                       __HIP_MEMORY_SCOPE_SYSTEM);
}
__device__ __forceinline__ void st_sys64(void* p, ull v) {
    __hip_atomic_store((ull*)p, v, __ATOMIC_RELAXED,
                       __HIP_MEMORY_SCOPE_SYSTEM);
}
__device__ __forceinline__ void st_sysi(int* p, int v) {
    __hip_atomic_store(p, v, __ATOMIC_RELAXED, __HIP_MEMORY_SCOPE_SYSTEM);
}
__device__ __forceinline__ void st_sysf(float* p, float v) {
    __hip_atomic_store(p, v, __ATOMIC_RELAXED, __HIP_MEMORY_SCOPE_SYSTEM);
}
__device__ __forceinline__ void st_sys_u4(ushort* p, ushort4 v) {
    union { ushort4 s; ull u; } c; c.s = v;
    st_sys64(p, c.u);
}
__device__ __forceinline__ bf8_t ld_sys_b128(const ushort* p) {
    union { ull u[2]; bf8_t v; } c;
    c.u[0] = ld_sys64(p);
    c.u[1] = ld_sys64(p + 4);
    return c.v;
}

// ---------------------------------------------------------------------------
// Shared-memory layouts.
// ---------------------------------------------------------------------------
struct CellsSM {                                // 61440 B
    float s2s[PB][132];                         // base2 fp32 (P2 -> P3)
    float s3f[PB][260];                         // base3 fp32 (P4 -> P5)
    float dsp[3][PB][KNN][3];
    int   jss[3][PB][KNN];
    union { ushort s1b[2][PB][72]; float hs[PB][64]; } u1;
    ushort s2b[2][PB][136];                     // s2 bf16 (P3 -> P4)
    ushort s3c[2][PB][264];                     // s3 bf16 (P5 -> P6)
};
union __align__(16) SM {                        // fused kernel: 61440 B
    CellsSM c;
    ushort  g[256 * 40 + 2 * 128 * 40];         // gemm staging, 40960 B
    float   kf[1544 + 4608 + 4608];             // knn, 43040 B
};
union __align__(16) GKSM {                      // fallback gemm+knn
    ushort  g[256 * 40 + 2 * 128 * 40];
    float   kf[1544 + 4608 + 4608];
};

// ---------------------------------------------------------------------------
// Group barrier: 64 blocks (bx%8 == g), fence-free. __syncthreads drains
// vmcnt (system stores are acked at the coherence point), the counter is a
// system-scope atomic, polls are relaxed system loads.
// ---------------------------------------------------------------------------
#define GRPN 64
__device__ __forceinline__ void group_barrier(int* __restrict__ bar, int g,
                                              int target, int tid) {
    __syncthreads();
    if (tid == 0) {
        __hip_atomic_fetch_add(&bar[g * 32], 1, __ATOMIC_RELAXED,
                               __HIP_MEMORY_SCOPE_SYSTEM);
        while (__hip_atomic_load(&bar[g * 32], __ATOMIC_RELAXED,
                                 __HIP_MEMORY_SCOPE_SYSTEM) < target)
            __builtin_amdgcn_s_sleep(4);
    }
    __syncthreads();
}

// ---------------------------------------------------------------------------
// KNN for 512 threads (exact top-8; selection under (d,idx) total order).
// idx outputs are system stores (consumed next phase).
// ---------------------------------------------------------------------------
__device__ __forceinline__ void knn512(
        const float* __restrict__ xqp, int xq_bs,
        const float* __restrict__ xsp, int xs_bs,
        int* __restrict__ idx1, int* __restrict__ idx2, int* __restrict__ idx3,
        float r2a, float r2b, float r2c,
        int ntile, int b, float* __restrict__ smf) {
    float* s   = smf;                           // NN*3 + NN/64 = 1544 floats
    float* cdp = smf + 1544;                    // [QB][TQK][KNN+1] = 4608
    int*   cip = (int*)(smf + 1544 + 4608);     // [QB][TQK][KNN+1] = 4608
    const int tid = threadIdx.x;

    {   // stage support points (512 threads, one each)
        int j = tid;
        const float* p = xsp + (long)b * xs_bs + j * 3;
        int o = 3 * j + (j >> 6);
        s[o + 0] = p[0]; s[o + 1] = p[1]; s[o + 2] = p[2];
    }
    __syncthreads();

    int qi  = tid >> 4;            // 0..31
    int sub = tid & 15;            // 0..15
    int n = ntile * QB + qi;
    const float* q = xqp + (long)b * xq_bs + n * 3;
    float qx = q[0], qy = q[1], qz2 = q[2];

    float bd[KNN];
    int   bi[KNN];
#pragma unroll
    for (int k = 0; k < KNN; ++k) { bd[k] = 1e30f; bi[k] = 0; }

    int j0 = sub * (NN / TQK);     // 32-point chunk (no 64-pad crossing)
    int sbase = 3 * j0 + (j0 >> 6);
#pragma unroll 4
    for (int jj = 0; jj < NN / TQK; ++jj) {
        float dx = s[sbase + 3 * jj + 0] - qx;
        float dy = s[sbase + 3 * jj + 1] - qy;
        float dz = s[sbase + 3 * jj + 2] - qz2;
        float d2 = fmaf(dx, dx, fmaf(dy, dy, dz * dz));
        if (d2 < bd[KNN - 1]) {
            bd[KNN - 1] = d2; bi[KNN - 1] = j0 + jj;
#pragma unroll
            for (int k = KNN - 1; k >= 1; --k) {
                if (bd[k] < bd[k - 1]) {
                    float td = bd[k]; bd[k] = bd[k - 1]; bd[k - 1] = td;
                    int   ti = bi[k]; bi[k] = bi[k - 1]; bi[k - 1] = ti;
                }
            }
        }
    }

    float* cdq = cdp + (qi * TQK + sub) * (KNN + 1);
    int*   ciq = cip + (qi * TQK + sub) * (KNN + 1);
#pragma unroll
    for (int k = 0; k < KNN; ++k) { cdq[k] = bd[k]; ciq[k] = bi[k]; }
    cdq[KNN] = 1e30f; ciq[KNN] = 0x7fffffff;
    __syncthreads();

    for (int stride = TQK / 2; stride >= 1; stride >>= 1) {
        if (sub < stride) {
            float* ca = cdp + (qi * TQK + sub) * (KNN + 1);
            float* cb = cdp + (qi * TQK + sub + stride) * (KNN + 1);
            int*   ja_p = cip + (qi * TQK + sub) * (KNN + 1);
            int*   jb_p = cip + (qi * TQK + sub + stride) * (KNN + 1);
            float rd[KNN]; int ri[KNN];
            int ia = 0, ib = 0;
#pragma unroll
            for (int k = 0; k < KNN; ++k) {
                float da = ca[ia], db = cb[ib];
                int   ja = ja_p[ia], jb = jb_p[ib];
                bool ta = (da < db) || (da == db && ja < jb);
                rd[k] = ta ? da : db; ri[k] = ta ? ja : jb;
                ia += ta ? 1 : 0; ib += ta ? 0 : 1;
            }
#pragma unroll
            for (int k = 0; k < KNN; ++k) { ca[k] = rd[k]; ja_p[k] = ri[k]; }
        }
        __syncthreads();
    }

    if (sub == 0) {
        long base = ((long)(b * NN + n)) * KNN;
        float* c0  = cdp + qi * TQK * (KNN + 1);
        int*   j0p = cip + qi * TQK * (KNN + 1);
        int i0 = j0p[0];
#pragma unroll
        for (int k = 0; k < KNN; ++k) {
            float d = c0[k]; int j = j0p[k];
            st_sysi(&idx1[base + k], (d <= r2a) ? j : i0);
            st_sysi(&idx2[base + k], (d <= r2b) ? j : i0);
            st_sysi(&idx3[base + k], (d <= r2c) ? j : i0);
        }
    }
}

// ---------------------------------------------------------------------------
// 512-thread GEMM tile, 128 rows x NC cols, K=N. One tile per block.
// A (s*, cross-phase) loads are system; B (weights, read-only) cached.
// G output bf16 via lane-paired 4B system stores. Bit-identical values.
// ---------------------------------------------------------------------------
template<int N, int NC>
__device__ __forceinline__ void gemmTileW(
        const ushort* __restrict__ Ah, const ushort* __restrict__ Al,
        const ushort* __restrict__ Bh, const ushort* __restrict__ Bl,
        ushort* __restrict__ G, int rb, int cb, int tid, ushort* lds) {
    const int row0 = rb * 128, c0 = cb * NC;
    ushort* ah = lds;                           // 128 x 40
    ushort* al = lds + 128 * 40;
    ushort* bh = lds + 256 * 40;                // NC x 40
    ushort* bl = lds + 256 * 40 + NC * 40;
    const int wv = tid >> 6, lane = tid & 63;
    const int m = lane & 15, quad = lane >> 4;
    const int lr = tid >> 2, ls = (tid & 3) * 8;    // 128 rows x 4 chunks

    f4_t acc[NC / 16];
#pragma unroll
    for (int ct = 0; ct < NC / 16; ++ct) acc[ct] = (f4_t){0.f, 0.f, 0.f, 0.f};

    bf8_t pa_h = ld_sys_b128(Ah + (long)(row0 + lr) * N + ls);
    bf8_t pa_l = ld_sys_b128(Al + (long)(row0 + lr) * N + ls);
    bf8_t pb_h, pb_l;
    const int lrB = (NC == 128) ? lr : (lr & 63);
    if (NC == 128) {
        pb_h = *(const bf8_t*)(Bh + (long)(c0 + lrB) * N + ls);
        pb_l = *(const bf8_t*)(Bl + (long)(c0 + lrB) * N + ls);
    } else {                       // NC==64: half threads h, half l
        const ushort* Bs = (tid < 256) ? Bh : Bl;
        pb_h = *(const bf8_t*)(Bs + (long)(c0 + lrB) * N + ls);
    }

    for (int k0 = 0; k0 < N; k0 += 32) {
        __syncthreads();
        *(bf8_t*)(ah + lr * 40 + ls) = pa_h;
        *(bf8_t*)(al + lr * 40 + ls) = pa_l;
        if (NC == 128) {
            *(bf8_t*)(bh + lrB * 40 + ls) = pb_h;
            *(bf8_t*)(bl + lrB * 40 + ls) = pb_l;
        } else {
            ushort* bs = (tid < 256) ? bh : bl;
            *(bf8_t*)(bs + lrB * 40 + ls) = pb_h;
        }
        __syncthreads();
        if (k0 + 32 < N) {
            int kn = k0 + 32;
            pa_h = ld_sys_b128(Ah + (long)(row0 + lr) * N + kn + ls);
            pa_l = ld_sys_b128(Al + (long)(row0 + lr) * N + kn + ls);
            if (NC == 128) {
                pb_h = *(const bf8_t*)(Bh + (long)(c0 + lrB) * N + kn + ls);
                pb_l = *(const bf8_t*)(Bl + (long)(c0 + lrB) * N + kn + ls);
            } else {
                const ushort* Bs = (tid < 256) ? Bh : Bl;
                pb_h = *(const bf8_t*)(Bs + (long)(c0 + lrB) * N + kn + ls);
            }
        }
        bf8_t a_h = *(const bf8_t*)(ah + (wv * 16 + m) * 40 + quad * 8);
        bf8_t a_l = *(const bf8_t*)(al + (wv * 16 + m) * 40 + quad * 8);
#pragma unroll
        for (int ct = 0; ct < NC / 16; ++ct) {
            bf8_t bth = *(const bf8_t*)(bh + (ct * 16 + m) * 40 + quad * 8);
            bf8_t btl = *(const bf8_t*)(bl + (ct * 16 + m) * 40 + quad * 8);
            acc[ct] = __builtin_amdgcn_mfma_f32_16x16x32_bf16(a_h, bth, acc[ct], 0, 0, 0);
            acc[ct] = __builtin_amdgcn_mfma_f32_16x16x32_bf16(a_h, btl, acc[ct], 0, 0, 0);
            acc[ct] = __builtin_amdgcn_mfma_f32_16x16x32_bf16(a_l, bth, acc[ct], 0, 0, 0);
        }
    }
#pragma unroll
    for (int ct = 0; ct < NC / 16; ++ct) {
        int col = c0 + ct * 16 + m;          // m even/odd lane pairs
#pragma unroll
        for (int r = 0; r < 4; ++r) {
            ushort v = f2b(acc[ct][r]);
            ushort vn = (ushort)__shfl_down((int)v, 1);
            if (!(m & 1))
                st_sys32(G + (long)(row0 + wv * 16 + quad * 4 + r) * N + col,
                         (uint)v | ((uint)vn << 16));
        }
    }
}

// One gemm work item per block: group-affine.
__device__ __forceinline__ void gemm_dispatch(
        int it, int tid, ushort* lds,
        const ushort* s1h, const ushort* s1l,
        const ushort* s2h, const ushort* s2l,
        const ushort* s3h, const ushort* s3l,
        const ushort* w1h, const ushort* w1l,
        const ushort* w2h, const ushort* w2l,
        const ushort* w3h, const ushort* w3l,
        ushort* G1, ushort* G2, ushort* G3) {
    int g = it & 7, j = it >> 3;               // j in [0,32)
    if (j < 16)
        gemmTileW<256, 128>(s3h, s3l, w3h, w3l, G3, g * 8 + (j & 7), j >> 3,
                            tid, lds);
    else if (j < 24)
        gemmTileW<128, 128>(s2h, s2l, w2h, w2l, G2, g * 8 + (j - 16), 0,
                            tid, lds);
    else
        gemmTileW<64, 64>(s1h, s1l, w1h, w1l, G1, g * 8 + (j - 24), 0,
                          tid, lds);
}

// ---------------------------------------------------------------------------
// Cells phase. Cross-phase reads (idx, G) and writes (s*) are system-scoped;
// positions/weights (read-only or write-once-then-read) stay cached.
// ---------------------------------------------------------------------------
__device__ __forceinline__ void cells_phase(
        bool first,
        const float* __restrict__ xq, int xq_bs,
        const float* __restrict__ xs, int xs_bs,
        const int* __restrict__ i1, const int* __restrict__ i2,
        const int* __restrict__ i3,
        const ushort* __restrict__ G1p, const ushort* __restrict__ G2p,
        const ushort* __restrict__ G3p,
        ushort* __restrict__ s1h, ushort* __restrict__ s1l,
        ushort* __restrict__ s2h, ushort* __restrict__ s2l,
        ushort* __restrict__ s3h, ushort* __restrict__ s3l,
        const float* __restrict__ W1, const float* __restrict__ b1,
        const float* __restrict__ W2, const float* __restrict__ b2,
        const float* __restrict__ W3, const float* __restrict__ b3,
        const ushort* __restrict__ w2fh, const ushort* __restrict__ w2fl,
        const ushort* __restrict__ w3fh, const ushort* __restrict__ w3fl,
        const ushort* __restrict__ wmh, const ushort* __restrict__ wml,
        const float* __restrict__ bm,
        const float* __restrict__ Wl, const float* __restrict__ bl,
        float* __restrict__ xnext, int xn_bs, int do_head,
        int blk, int tid, CellsSM& sm) {
    const int xcd = blk & 7, slot = blk >> 3;
    const int b   = xcd * 2 + (slot >> 5);     // batch <-> group affinity
    const int n0  = (slot & 31) << 4;
    const long row0 = (long)b * NN + n0;
    const long bN = (long)b * NN;
    const int wv = tid >> 6, lane = tid & 63;
    const int fm = lane & 15, quad = lane >> 4;

    // P0: neighbor indices + displacements for all 3 radii
    for (int t = tid; t < 3 * PB * KNN; t += 512) {
        int r = t >> 7, rem = t & 127, p = rem >> 3, k = rem & 7;
        const int* ix = (r == 0) ? i1 : ((r == 1) ? i2 : i3);
        int j = ld_sysi(&ix[(row0 + p) * KNN + k]);
        sm.jss[r][p][k] = j;
        const float* sp = xs + (long)b * xs_bs + j * 3;
        const float* qp = xq + (long)b * xq_bs + (n0 + p) * 3;
        sm.dsp[r][p][k][0] = sp[0] - qp[0];
        sm.dsp[r][p][k][1] = sp[1] - qp[1];
        sm.dsp[r][p][k][2] = sp[2] - qp[2];
    }
    __syncthreads();

    // P1: cell1 combine -> s1 bf16 (LDS) + lane-paired system global store
    {
        int co = tid & 63, q = tid >> 6;
        float g1r[2][KNN];
        if (!first) {
#pragma unroll
            for (int r = 0; r < 2; ++r)
#pragma unroll
                for (int k = 0; k < KNN; ++k) {
                    uint vv = ld_sys32(G1p + (bN + sm.jss[0][2 * q + r][k]) * 64
                                       + (co & ~1));
                    ushort hv = (co & 1) ? (ushort)(vv >> 16) : (ushort)vv;
                    g1r[r][k] = b2f(hv);
                }
        }
        float wx = W1[co], wy = W1[64 + co], wz = W1[128 + co];
        float bz = b1[co];
#pragma unroll
        for (int r = 0; r < 2; ++r) {
            int p = 2 * q + r;
            float acc = -1e30f;
#pragma unroll
            for (int k = 0; k < KNN; ++k) {
                float v = fmaf(sm.dsp[0][p][k][0], wx, bz);
                v = fmaf(sm.dsp[0][p][k][1], wy, v);
                v = fmaf(sm.dsp[0][p][k][2], wz, v);
                if (!first) v += g1r[r][k];
                acc = fmaxf(acc, v);
            }
            ushort h = f2b(acc);
            ushort l = f2b(acc - b2f(h));
            sm.u1.s1b[0][p][co] = h;
            sm.u1.s1b[1][p][co] = l;
            ushort hn = (ushort)__shfl_down((int)h, 1);
            ushort ln = (ushort)__shfl_down((int)l, 1);
            if (!(co & 1)) {
                st_sys32(s1h + (row0 + p) * 64 + co, (uint)h | ((uint)hn << 16));
                st_sys32(s1l + (row0 + p) * 64 + co, (uint)l | ((uint)ln << 16));
            }
        }
    }
    __syncthreads();

    // G2 gathers prefetched (system 8B -> fp32), hidden behind base2 MFMA
    float4 g2r[KNN];
    {
        int c4 = tid & 31, g = tid >> 5;
        if (!first) {
#pragma unroll
            for (int k = 0; k < KNN; ++k) {
                ull v = ld_sys64(&G2p[(bN + sm.jss[1][g][k]) * 128 + c4 * 4]);
                g2r[k] = make_float4(b2f((ushort)v), b2f((ushort)(v >> 16)),
                                     b2f((ushort)(v >> 32)), b2f((ushort)(v >> 48)));
            }
        }
    }

    // P2: base2 = s1 @ W2f + b2 on MFMA -> s2s
    {
        int col = wv * 16 + fm;
        float bz = b2[col];
        f4_t acc = {bz, bz, bz, bz};
#pragma unroll
        for (int k0 = 0; k0 < 64; k0 += 32) {
            bf8_t ah = *(const bf8_t*)&sm.u1.s1b[0][fm][k0 + quad * 8];
            bf8_t al = *(const bf8_t*)&sm.u1.s1b[1][fm][k0 + quad * 8];
            bf8_t bh = *(const bf8_t*)(w2fh + col * 64 + k0 + quad * 8);
            bf8_t bl = *(const bf8_t*)(w2fl + col * 64 + k0 + quad * 8);
            acc = __builtin_amdgcn_mfma_f32_16x16x32_bf16(ah, bh, acc, 0, 0, 0);
            acc = __builtin_amdgcn_mfma_f32_16x16x32_bf16(ah, bl, acc, 0, 0, 0);
            acc = __builtin_amdgcn_mfma_f32_16x16x32_bf16(al, bh, acc, 0, 0, 0);
        }
#pragma unroll
        for (int r = 0; r < 4; ++r) sm.s2s[quad * 4 + r][col] = acc[r];
    }
    __syncthreads();

    // P3: combine2 -> s2 bf16 (LDS) + system global store (8B)
    {
        int c4 = tid & 31, g = tid >> 5;
        float4 bse = *(float4*)&sm.s2s[g][c4 * 4];
        float4 wx = ((const float4*)W2)[c4];
        float4 wy = ((const float4*)(W2 + 128))[c4];
        float4 wz = ((const float4*)(W2 + 256))[c4];
        float4 m = make_float4(-1e30f, -1e30f, -1e30f, -1e30f);
#pragma unroll
        for (int k = 0; k < KNN; ++k) {
            float dx = sm.dsp[1][g][k][0], dy = sm.dsp[1][g][k][1],
                  dz = sm.dsp[1][g][k][2];
            float4 v;
            v.x = fmaf(dz, wz.x, fmaf(dy, wy.x, fmaf(dx, wx.x, bse.x)));
            v.y = fmaf(dz, wz.y, fmaf(dy, wy.y, fmaf(dx, wx.y, bse.y)));
            v.z = fmaf(dz, wz.z, fmaf(dy, wy.z, fmaf(dx, wx.z, bse.z)));
            v.w = fmaf(dz, wz.w, fmaf(dy, wy.w, fmaf(dx, wx.w, bse.w)));
            if (!first) {
                v.x += g2r[k].x; v.y += g2r[k].y;
                v.z += g2r[k].z; v.w += g2r[k].w;
            }
            m.x = fmaxf(m.x, v.x); m.y = fmaxf(m.y, v.y);
            m.z = fmaxf(m.z, v.z); m.w = fmaxf(m.w, v.w);
        }
        ushort4 mh, ml;
        mh.x = f2b(m.x); ml.x = f2b(m.x - b2f(mh.x));
        mh.y = f2b(m.y); ml.y = f2b(m.y - b2f(mh.y));
        mh.z = f2b(m.z); ml.z = f2b(m.z - b2f(mh.z));
        mh.w = f2b(m.w); ml.w = f2b(m.w - b2f(mh.w));
        *(ushort4*)&sm.s2b[0][g][c4 * 4] = mh;
        *(ushort4*)&sm.s2b[1][g][c4 * 4] = ml;
        st_sys_u4(&s2h[(row0 + g) * 128 + c4 * 4], mh);
        st_sys_u4(&s2l[(row0 + g) * 128 + c4 * 4], ml);
    }
    __syncthreads();

    // G3 gathers prefetched (system 8B -> fp32), hidden behind base3 MFMA
    float4 g3r[2][KNN];
    {
        int c4 = tid & 63, g = tid >> 6;
        if (!first) {
#pragma unroll
            for (int r = 0; r < 2; ++r)
#pragma unroll
                for (int k = 0; k < KNN; ++k) {
                    ull v = ld_sys64(&G3p[(bN + sm.jss[2][2 * g + r][k]) * 256 + c4 * 4]);
                    g3r[r][k] = make_float4(b2f((ushort)v), b2f((ushort)(v >> 16)),
                                            b2f((ushort)(v >> 32)), b2f((ushort)(v >> 48)));
                }
        }
    }

    // P4: base3 = s2 @ W3f + b3 on MFMA -> s3f (2 column tiles per wave)
    {
        int col0 = wv * 16 + fm, col1 = (wv + 8) * 16 + fm;
        float bz0 = b3[col0], bz1 = b3[col1];
        f4_t a0 = {bz0, bz0, bz0, bz0};
        f4_t a1 = {bz1, bz1, bz1, bz1};
#pragma unroll
        for (int k0 = 0; k0 < 128; k0 += 32) {
            bf8_t ah = *(const bf8_t*)&sm.s2b[0][fm][k0 + quad * 8];
            bf8_t al = *(const bf8_t*)&sm.s2b[1][fm][k0 + quad * 8];
            bf8_t b0h = *(const bf8_t*)(w3fh + col0 * 128 + k0 + quad * 8);
            bf8_t b0l = *(const bf8_t*)(w3fl + col0 * 128 + k0 + quad * 8);
            bf8_t b1h = *(const bf8_t*)(w3fh + col1 * 128 + k0 + quad * 8);
            bf8_t b1l = *(const bf8_t*)(w3fl + col1 * 128 + k0 + quad * 8);
            a0 = __builtin_amdgcn_mfma_f32_16x16x32_bf16(ah, b0h, a0, 0, 0, 0);
            a0 = __builtin_amdgcn_mfma_f32_16x16x32_bf16(ah, b0l, a0, 0, 0, 0);
            a0 = __builtin_amdgcn_mfma_f32_16x16x32_bf16(al, b0h, a0, 0, 0, 0);
            a1 = __builtin_amdgcn_mfma_f32_16x16x32_bf16(ah, b1h, a1, 0, 0, 0);
            a1 = __builtin_amdgcn_mfma_f32_16x16x32_bf16(ah, b1l, a1, 0, 0, 0);
            a1 = __builtin_amdgcn_mfma_f32_16x16x32_bf16(al, b1h, a1, 0, 0, 0);
        }
#pragma unroll
        for (int r = 0; r < 4; ++r) {
            sm.s3f[quad * 4 + r][col0] = a0[r];
            sm.s3f[quad * 4 + r][col1] = a1[r];
        }
    }
    __syncthreads();

    // P5: combine3 -> s3 bf16 (LDS) + system global store (8B)
    {
        int c4 = tid & 63, g = tid >> 6;
        float4 wx = ((const float4*)W3)[c4];
        float4 wy = ((const float4*)(W3 + 256))[c4];
        float4 wz = ((const float4*)(W3 + 512))[c4];
#pragma unroll
        for (int r = 0; r < 2; ++r) {
            int p = 2 * g + r;
            float4 bse = *(float4*)&sm.s3f[p][c4 * 4];
            float4 m = make_float4(-1e30f, -1e30f, -1e30f, -1e30f);
#pragma unroll
            for (int k = 0; k < KNN; ++k) {
                float dx = sm.dsp[2][p][k][0], dy = sm.dsp[2][p][k][1],
                      dz = sm.dsp[2][p][k][2];
                float4 v;
                v.x = fmaf(dz, wz.x, fmaf(dy, wy.x, fmaf(dx, wx.x, bse.x)));
                v.y = fmaf(dz, wz.y, fmaf(dy, wy.y, fmaf(dx, wx.y, bse.y)));
                v.z = fmaf(dz, wz.z, fmaf(dy, wy.z, fmaf(dx, wx.z, bse.z)));
                v.w = fmaf(dz, wz.w, fmaf(dy, wy.w, fmaf(dx, wx.w, bse.w)));
                if (!first) {
                    v.x += g3r[r][k].x; v.y += g3r[r][k].y;
                    v.z += g3r[r][k].z; v.w += g3r[r][k].w;
                }
                m.x = fmaxf(m.x, v.x); m.y = fmaxf(m.y, v.y);
                m.z = fmaxf(m.z, v.z); m.w = fmaxf(m.w, v.w);
            }
            ushort4 mh, ml;
            mh.x = f2b(m.x); ml.x = f2b(m.x - b2f(mh.x));
            mh.y = f2b(m.y); ml.y = f2b(m.y - b2f(mh.y));
            mh.z = f2b(m.z); ml.z = f2b(m.z - b2f(mh.z));
            mh.w = f2b(m.w); ml.w = f2b(m.w - b2f(mh.w));
            *(ushort4*)&sm.s3c[0][p][c4 * 4] = mh;
            *(ushort4*)&sm.s3c[1][p][c4 * 4] = ml;
            st_sys_u4(&s3h[(row0 + p) * 256 + c4 * 4], mh);
            st_sys_u4(&s3l[(row0 + p) * 256 + c4 * 4], ml);
        }
    }

    // P6: prediction head — h = relu(s3 @ Wm + bm) on MFMA, then motion
    if (do_head) {
        __syncthreads();
        if (wv < 4) {
            int col = wv * 16 + fm;
            float bz = bm[col];
            f4_t acc = {bz, bz, bz, bz};
#pragma unroll
            for (int k0 = 0; k0 < 256; k0 += 32) {
                bf8_t ah = *(const bf8_t*)&sm.s3c[0][fm][k0 + quad * 8];
                bf8_t al = *(const bf8_t*)&sm.s3c[1][fm][k0 + quad * 8];
                bf8_t bh = *(const bf8_t*)(wmh + col * 256 + k0 + quad * 8);
                bf8_t bl = *(const bf8_t*)(wml + col * 256 + k0 + quad * 8);
                acc = __builtin_amdgcn_mfma_f32_16x16x32_bf16(ah, bh, acc, 0, 0, 0);
                acc = __builtin_amdgcn_mfma_f32_16x16x32_bf16(ah, bl, acc, 0, 0, 0);
                acc = __builtin_amdgcn_mfma_f32_16x16x32_bf16(al, bh, acc, 0, 0, 0);
            }
            __syncthreads();   // u1.s1b dead since P2; reuse as hs
#pragma unroll
            for (int r = 0; r < 4; ++r)
                sm.u1.hs[quad * 4 + r][col] = fmaxf(acc[r], 0.f);
        } else {
            __syncthreads();
        }
        __syncthreads();
        if (tid < PB * 3) {
            int p = tid / 3, d = tid % 3;
            float m = bl[d];
#pragma unroll 4
            for (int c = 0; c < 64; ++c)
                m = fmaf(sm.u1.hs[p][c], Wl[c * 3 + d], m);
            const float* qp = xq + (long)b * xq_bs + (n0 + p) * 3;
            st_sysf(&xnext[(long)b * xn_bs + (n0 + p) * 3 + d], qp[d] + m);
        }
    }
}

// ---------------------------------------------------------------------------
// Weight conversion helper (flat id). Plain stores; ordered by grid.sync.
// ---------------------------------------------------------------------------
__device__ __forceinline__ void convW_one(int id,
        const float* __restrict__ W1, const float* __restrict__ W2,
        const float* __restrict__ W3, const float* __restrict__ Wm,
        ushort* w1h, ushort* w1l, ushort* w2h, ushort* w2l,
        ushort* w3h, ushort* w3l, ushort* w2fh, ushort* w2fl,
        ushort* w3fh, ushort* w3fl, ushort* wmh, ushort* wml) {
    float v; ushort* ph; ushort* pl; int idx;
    if (id < 4096)        { int n = id >> 6, k = id & 63;
        v = W1[(3 + k) * 64 + n];   ph = w1h;  pl = w1l;  idx = id; }
    else if (id < 20480)  { int u = id - 4096, n = u >> 7, k = u & 127;
        v = W2[(67 + k) * 128 + n]; ph = w2h;  pl = w2l;  idx = u; }
    else if (id < 86016)  { int u = id - 20480, n = u >> 8, k = u & 255;
        v = W3[(131 + k) * 256 + n]; ph = w3h; pl = w3l;  idx = u; }
    else if (id < 94208)  { int u = id - 86016, n = u >> 6, k = u & 63;
        v = W2[(3 + k) * 128 + n];  ph = w2fh; pl = w2fl; idx = u; }
    else if (id < 126976) { int u = id - 94208, n = u >> 7, k = u & 127;
        v = W3[(3 + k) * 256 + n];  ph = w3fh; pl = w3fl; idx = u; }
    else if (id < 143360) { int u = id - 126976, n = u >> 8, k = u & 255;
        v = Wm[k * 64 + n];         ph = wmh;  pl = wml;  idx = u; }
    else return;
    ushort h = f2b(v);
    ph[idx] = h; pl[idx] = f2b(v - b2f(h));
}

// ---------------------------------------------------------------------------
// FUSED cooperative kernel. One grid.sync after init (weights); all later
// syncs are fence-free group barriers (data is system-scoped).
// ---------------------------------------------------------------------------
__global__ __launch_bounds__(512, 4) void fused_kernel(
        const float* frames, float* out,
        ushort* G1, ushort* G2, ushort* G3,
        ushort* s1h, ushort* s1l, ushort* s2h, ushort* s2l,
        ushort* s3h, ushort* s3l,
        ushort* w1h, ushort* w1l, ushort* w2h, ushort* w2l,
        ushort* w3h, ushort* w3l,
        ushort* w2fh, ushort* w2fl, ushort* w3fh, ushort* w3fl,
        ushort* wmh, ushort* wml,
        int* idx1w, int* idx2w, int* idx3w, int* bar,
        const float* W1, const float* b1, const float* W2, const float* b2,
        const float* W3, const float* b3, const float* Wm, const float* bm,
        const float* Wl, const float* bl,
        float r2a, float r2b, float r2c) {
    __shared__ SM sm;
    cg::grid_group grid = cg::this_grid();
    const int bx = blockIdx.x, tid = threadIdx.x;
    const int grp = bx & 7;
    const int FB = SEQ * NN * 3, OB = 6 * NN * 3;
    const long BNK = (long)BB * NN * KNN;

    // ---- init: zero barrier counters + weight conversion + knn slice 0 ----
    if (bx == 0 && tid < 8) st_sysi(&bar[tid * 32], 0);
    convW_one(bx * 512 + tid, W1, W2, W3, Wm,
              w1h, w1l, w2h, w2l, w3h, w3l,
              w2fh, w2fl, w3fh, w3fl, wmh, wml);
    if (bx < 256) {
        int xcd = bx & 7, slot = bx >> 3;
        int b = xcd * 2 + (slot & 1), ntile = slot >> 1;
        knn512(frames, FB, frames, FB, idx1w, idx2w, idx3w,
               r2a, r2b, r2c, ntile, b, sm.kf);
    }
    grid.sync();      // orders weights + counters + knn slot0 for all groups

    int ph = 1;       // monotonic group-barrier phase

    for (int t = 0; t < SEQ; ++t) {
        const float* xq; int xq_bs; const float* xs; int xs_bs;
        if (t < 6)       { xq = frames + (long)t * NN * 3;        xq_bs = FB; }
        else if (t == 6) { xq = frames + 5L * NN * 3;             xq_bs = FB; }
        else             { xq = out + (long)(t - 7) * NN * 3;     xq_bs = OB; }
        if (t == 0)      { xs = xq;                               xs_bs = xq_bs; }
        else if (t <= 6) { xs = frames + (long)(t - 1) * NN * 3;  xs_bs = FB; }
        else if (t == 7) { xs = frames + 5L * NN * 3;             xs_bs = FB; }
        else             { xs = out + (long)(t - 8) * NN * 3;     xs_bs = OB; }
        int slot = (t <= 6) ? t : 0;
        const int* i1 = idx1w + slot * BNK;
        const int* i2 = idx2w + slot * BNK;
        const int* i3 = idx3w + slot * BNK;
        int do_head = (t >= 6);
        float* xnext = do_head ? out + (long)(t - 6) * NN * 3 : nullptr;

        cells_phase(t == 0, xq, xq_bs, xs, xs_bs, i1, i2, i3,
                    G1, G2, G3, s1h, s1l, s2h, s2l, s3h, s3l,
                    W1, b1, W2, b2, W3, b3,
                    w2fh, w2fl, w3fh, w3fl, wmh, wml, bm,
                    Wl, bl, xnext, OB, do_head, bx, tid, sm.c);

        if (t == SEQ - 1) break;
        group_barrier(bar, grp, GRPN * ph, tid); ++ph;

        // ---- gemm + knn(t+1) phase (all work is group-local) ----
        if (bx < 256) {
            int tn = t + 1;
            const float* kq; int kq_bs; const float* ksp; int ks_bs; int kslot;
            if (tn <= 6) {
                int qz = tn < 5 ? tn : 5;
                kq = frames + (long)qz * NN * 3;        kq_bs = FB;
                ksp = frames + (long)(tn - 1) * NN * 3; ks_bs = FB;
                kslot = tn;
            } else {
                kq = out + (long)(tn - 7) * NN * 3;     kq_bs = OB;
                if (tn == 7) { ksp = frames + 5L * NN * 3;          ks_bs = FB; }
                else         { ksp = out + (long)(tn - 8) * NN * 3; ks_bs = OB; }
                kslot = 0;
            }
            int xcd = bx & 7, slot2 = bx >> 3;
            int b = xcd * 2 + (slot2 & 1), ntile = slot2 >> 1;
            knn512(kq, kq_bs, ksp, ks_bs,
                   idx1w + (long)kslot * BNK, idx2w + (long)kslot * BNK,
                   idx3w + (long)kslot * BNK,
                   r2a, r2b, r2c, ntile, b, sm.kf);
        } else {
            gemm_dispatch(bx - 256, tid, sm.g,
                          s1h, s1l, s2h, s2l, s3h, s3l,
                          w1h, w1l, w2h, w2l, w3h, w3l, G1, G2, G3);
        }
        group_barrier(bar, grp, GRPN * ph, tid); ++ph;
    }
}

// ---------------------------------------------------------------------------
// FALLBACK multi-kernel schedule (same device functions; kernel boundaries
// provide coherence; system ops are harmless there).
// ---------------------------------------------------------------------------
__global__ __launch_bounds__(512) void init512_kernel(
        const float* __restrict__ frames, int FB,
        int* __restrict__ i1, int* __restrict__ i2, int* __restrict__ i3,
        float r2a, float r2b, float r2c,
        const float* __restrict__ W1, const float* __restrict__ W2,
        const float* __restrict__ W3, const float* __restrict__ Wm,
        ushort* w1h, ushort* w1l, ushort* w2h, ushort* w2l,
        ushort* w3h, ushort* w3l, ushort* w2fh, ushort* w2fl,
        ushort* w3fh, ushort* w3fl, ushort* wmh, ushort* wml) {
    __shared__ float kf[1544 + 4608 + 4608];
    int bx = blockIdx.x;
    if (bx < 256) {
        int xcd = bx & 7, slot = bx >> 3;
        int b = xcd * 2 + (slot & 1), ntile = slot >> 1;
        knn512(frames, FB, frames, FB, i1, i2, i3, r2a, r2b, r2c,
               ntile, b, kf);
        return;
    }
    convW_one((bx - 256) * 512 + threadIdx.x, W1, W2, W3, Wm,
              w1h, w1l, w2h, w2l, w3h, w3l,
              w2fh, w2fl, w3fh, w3fl, wmh, wml);
}

__global__ __launch_bounds__(512) void cells512_kernel(
        int first,
        const float* __restrict__ xq, int xq_bs,
        const float* __restrict__ xs, int xs_bs,
        const int* __restrict__ i1, const int* __restrict__ i2,
        const int* __restrict__ i3,
        const ushort* __restrict__ G1p, const ushort* __restrict__ G2p,
        const ushort* __restrict__ G3p,
        ushort* s1h, ushort* s1l, ushort* s2h, ushort* s2l,
        ushort* s3h, ushort* s3l,
        const float* __restrict__ W1, const float* __restrict__ b1,
        const float* __restrict__ W2, const float* __restrict__ b2,
        const float* __restrict__ W3, const float* __restrict__ b3,
        const ushort* __restrict__ w2fh, const ushort* __restrict__ w2fl,
        const ushort* __restrict__ w3fh, const ushort* __restrict__ w3fl,
        const ushort* __restrict__ wmh, const ushort* __restrict__ wml,
        const float* __restrict__ bm,
        const float* __restrict__ Wl, const float* __restrict__ bl,
        float* xnext, int xn_bs, int do_head) {
    __shared__ CellsSM sm;
    cells_phase(first != 0, xq, xq_bs, xs, xs_bs, i1, i2, i3,
                G1p, G2p, G3p, s1h, s1l, s2h, s2l, s3h, s3l,
                W1, b1, W2, b2, W3, b3, w2fh, w2fl, w3fh, w3fl,
                wmh, wml, bm, Wl, bl, xnext, xn_bs, do_head,
                blockIdx.x, threadIdx.x, sm);
}

__global__ __launch_bounds__(512) void gemmknn512_kernel(
        const ushort* s1h, const ushort* s1l,
        const ushort* s2h, const ushort* s2l,
        const ushort* s3h, const ushort* s3l,
        const ushort* w1h, const ushort* w1l,
        const ushort* w2h, const ushort* w2l,
        const ushort* w3h, const ushort* w3l,
        ushort* G1, ushort* G2, ushort* G3,
        const float* __restrict__ kq, int kq_bs,
        const float* __restrict__ ks, int ks_bs,
        int* ki1, int* ki2, int* ki3,
        float r2a, float r2b, float r2c) {
    __shared__ GKSM sm;
    int bx = blockIdx.x, tid = threadIdx.x;
    if (bx < 256) {
        int xcd = bx & 7, slot = bx >> 3;
        int b = xcd * 2 + (slot & 1), ntile = slot >> 1;
        knn512(kq, kq_bs, ks, ks_bs, ki1, ki2, ki3, r2a, r2b, r2c,
               ntile, b, sm.kf);
        return;
    }
    gemm_dispatch(bx - 256, tid, sm.g,
                  s1h, s1l, s2h, s2l, s3h, s3l,
                  w1h, w1l, w2h, w2l, w3h, w3l, G1, G2, G3);
}

extern "C" void kernel_launch(void* const* d_in, const int* in_sizes, int n_in,
                              void* d_out, int out_size, void* d_ws, size_t ws_size,
                              hipStream_t stream) {
    const float* frames = (const float*)d_in[0];
    const float* W1 = (const float*)d_in[1]; const float* b1 = (const float*)d_in[2];
    const float* W2 = (const float*)d_in[3]; const float* b2 = (const float*)d_in[4];
    const float* W3 = (const float*)d_in[5]; const float* b3 = (const float*)d_in[6];
    const float* Wm = (const float*)d_in[7]; const float* bm = (const float*)d_in[8];
    const float* Wl = (const float*)d_in[9]; const float* bl = (const float*)d_in[10];
    float* out = (float*)d_out;

    const long M = (long)BB * NN;    // 8192
    ushort* us = (ushort*)d_ws;
    ushort* G1b = us; us += M * 64;   // bf16 G arrays
    ushort* G2b = us; us += M * 128;
    ushort* G3b = us; us += M * 256;
    ushort* s1h = us; us += M * 64;   ushort* s1l = us; us += M * 64;
    ushort* s2h = us; us += M * 128;  ushort* s2l = us; us += M * 128;
    ushort* s3h = us; us += M * 256;  ushort* s3l = us; us += M * 256;
    ushort* w1h = us; us += 4096;     ushort* w1l = us; us += 4096;
    ushort* w2h = us; us += 16384;    ushort* w2l = us; us += 16384;
    ushort* w3h = us; us += 65536;    ushort* w3l = us; us += 65536;
    ushort* w2fh = us; us += 8192;    ushort* w2fl = us; us += 8192;
    ushort* w3fh = us; us += 32768;   ushort* w3fl = us; us += 32768;
    ushort* wmh = us; us += 16384;    ushort* wml = us; us += 16384;
    us += (size_t)us & 1;             // even-align for int
    const long BNK = M * KNN;
    int* ip = (int*)us;
    int* idx1w = ip; ip += 7 * BNK;
    int* idx2w = ip; ip += 7 * BNK;
    int* idx3w = ip; ip += 7 * BNK;
    int* bar   = ip; ip += 8 * 32;    // 8 group counters, 128B apart

    double ra = 4.0 + 1e-6, rbd = 8.0 + 1e-6, rc = 12.0 + 1e-6;
    float r2a = (float)(ra * ra), r2b = (float)(rbd * rbd), r2c = (float)(rc * rc);

    const int FB = SEQ * NN * 3;
    const int OB = 6 * NN * 3;

    // ---- capture-safe cooperative feasibility check (cached) ----
    static int g_coop = -1;
    if (g_coop < 0) {
        int attr = 0, dev = 0, nb = 0;
        hipGetDevice(&dev);
        hipDeviceGetAttribute(&attr, hipDeviceAttributeCooperativeLaunch, dev);
        hipDeviceProp_t prop{};
        hipGetDeviceProperties(&prop, dev);
        if (attr &&
            hipOccupancyMaxActiveBlocksPerMultiprocessor(
                &nb, fused_kernel, 512, 0) == hipSuccess &&
            nb * prop.multiProcessorCount >= 512)
            g_coop = 1;
        else
            g_coop = 0;
    }

    bool did_coop = false;
    if (g_coop == 1) {
        void* args[] = {
            (void*)&frames, (void*)&out,
            (void*)&G1b, (void*)&G2b, (void*)&G3b,
            (void*)&s1h, (void*)&s1l, (void*)&s2h, (void*)&s2l,
            (void*)&s3h, (void*)&s3l,
            (void*)&w1h, (void*)&w1l, (void*)&w2h, (void*)&w2l,
            (void*)&w3h, (void*)&w3l,
            (void*)&w2fh, (void*)&w2fl, (void*)&w3fh, (void*)&w3fl,
            (void*)&wmh, (void*)&wml,
            (void*)&idx1w, (void*)&idx2w, (void*)&idx3w, (void*)&bar,
            (void*)&W1, (void*)&b1, (void*)&W2, (void*)&b2,
            (void*)&W3, (void*)&b3, (void*)&Wm, (void*)&bm,
            (void*)&Wl, (void*)&bl,
            (void*)&r2a, (void*)&r2b, (void*)&r2c
        };
        hipError_t e = hipLaunchCooperativeKernel((const void*)fused_kernel,
                                                  dim3(512), dim3(512),
                                                  args, 0, stream);
        did_coop = (e == hipSuccess);
        if (!did_coop) g_coop = 0;
    }

    if (!did_coop) {
        // ---- proven multi-kernel schedule ----
        init512_kernel<<<536, 512, 0, stream>>>(
            frames, FB, idx1w, idx2w, idx3w, r2a, r2b, r2c,
            W1, W2, W3, Wm, w1h, w1l, w2h, w2l, w3h, w3l,
            w2fh, w2fl, w3fh, w3fl, wmh, wml);

        for (int t = 0; t < SEQ; ++t) {
            const float* xq; int xq_bs; const float* xs; int xs_bs;
            if (t < 6)       { xq = frames + (long)t * NN * 3;        xq_bs = FB; }
            else if (t == 6) { xq = frames + 5L * NN * 3;             xq_bs = FB; }
            else             { xq = out + (long)(t - 7) * NN * 3;     xq_bs = OB; }
            if (t == 0)      { xs = xq;                               xs_bs = xq_bs; }
            else if (t <= 6) { xs = frames + (long)(t - 1) * NN * 3;  xs_bs = FB; }
            else if (t == 7) { xs = frames + 5L * NN * 3;             xs_bs = FB; }
            else             { xs = out + (long)(t - 8) * NN * 3;     xs_bs = OB; }

            int slot = (t <= 6) ? t : 0;
            int* i1 = idx1w + (long)slot * BNK;
            int* i2 = idx2w + (long)slot * BNK;
            int* i3 = idx3w + (long)slot * BNK;

            int do_head = (t >= 6);
            float* xnext = do_head ? out + (long)(t - 6) * NN * 3 : nullptr;

            cells512_kernel<<<BB * NN / PB, 512, 0, stream>>>(
                t == 0 ? 1 : 0, xq, xq_bs, xs, xs_bs, i1, i2, i3,
                G1b, G2b, G3b, s1h, s1l, s2h, s2l, s3h, s3l,
                W1, b1, W2, b2, W3, b3,
                w2fh, w2fl, w3fh, w3fl, wmh, wml, bm,
                Wl, bl, xnext, OB, do_head);

            if (t < SEQ - 1) {
                int tn = t + 1;
                const float* kq; int kq_bs; const float* ksp; int ks_bs; int kslot;
                if (tn <= 6) {
                    int qz = tn < 5 ? tn : 5;
                    kq = frames + (long)qz * NN * 3;        kq_bs = FB;
                    ksp = frames + (long)(tn - 1) * NN * 3; ks_bs = FB;
                    kslot = tn;
                } else {
                    kq = out + (long)(tn - 7) * NN * 3;     kq_bs = OB;
                    if (tn == 7) { ksp = frames + 5L * NN * 3;          ks_bs = FB; }
                    else         { ksp = out + (long)(tn - 8) * NN * 3; ks_bs = OB; }
                    kslot = 0;
                }
                gemmknn512_kernel<<<512, 512, 0, stream>>>(
                    s1h, s1l, s2h, s2l, s3h, s3l,
                    w1h, w1l, w2h, w2l, w3h, w3l,
                    G1b, G2b, G3b,
                    kq, kq_bs, ksp, ks_bs,
                    idx1w + (long)kslot * BNK, idx2w + (long)kslot * BNK,
                    idx3w + (long)kslot * BNK,
                    r2a, r2b, r2c);
            }
        }
    }
}